// Round 1
// baseline (1015.929 us; speedup 1.0000x reference)
//
#include <hip/hip_runtime.h>

// ---------------------------------------------------------------------------
// GraphTransformer: GCNConv(64->64) + ReLU -> TransformerConv(heads=1) -> GCNConv(64->64)
// N=50000 nodes, E=800000 edges, D=64. All fp32.
// Round 1: straightforward multi-kernel implementation. Edge scatters use
// fp32 atomics (wave-per-edge, lane-per-feature). GEMMs are LDS-staged.
// ---------------------------------------------------------------------------

#define D 64

// ---- node init: deg=1 (self loop), segment-max init, z=0 -------------------
__global__ void init_node_kernel(float* __restrict__ deg, int* __restrict__ mmax,
                                 float* __restrict__ z, int n) {
    int i = blockIdx.x * blockDim.x + threadIdx.x;
    if (i < n) {
        deg[i]  = 1.0f;          // self-loop contributes 1
        mmax[i] = 0x80000000;    // mapped -inf (below all mapped reals)
        z[i]    = 0.0f;
    }
}

// ---- degree accumulation over dst ------------------------------------------
__global__ void deg_kernel(const int* __restrict__ dst, float* __restrict__ deg, int e) {
    int i = blockIdx.x * blockDim.x + threadIdx.x;
    if (i < e) atomicAdd(&deg[dst[i]], 1.0f);
}

__global__ void dinv_kernel(float* __restrict__ deg, int n) {
    int i = blockIdx.x * blockDim.x + threadIdx.x;
    if (i < n) deg[i] = rsqrtf(deg[i]);   // deg >= 1 always (self-loop)
}

// ---- Y[n,64] = X[n,64] @ W[64,64] (+bias) ----------------------------------
// 256 threads = 4 rows x 64 cols. W staged in LDS (16KB).
__global__ __launch_bounds__(256) void gemm64_kernel(const float* __restrict__ X,
                                                     const float* __restrict__ W,
                                                     const float* __restrict__ bias,
                                                     float* __restrict__ Y, int n) {
    __shared__ float sW[64 * 64];
    __shared__ float sX[4 * 64];
    int t = threadIdx.x;
    #pragma unroll
    for (int i = 0; i < 16; ++i) sW[t + 256 * i] = W[t + 256 * i];
    int r = t >> 6;
    int j = t & 63;
    int row = blockIdx.x * 4 + r;
    sX[t] = (row < n) ? X[row * D + j] : 0.0f;
    __syncthreads();
    float acc = bias ? bias[j] : 0.0f;
    #pragma unroll
    for (int k = 0; k < 64; ++k) acc = fmaf(sX[r * 64 + k], sW[k * 64 + j], acc);
    if (row < n) Y[row * D + j] = acc;
}

// ---- out[i][j] = xw[i][j] * dinv[i]^2  (GCN self-loop term, init accum) ----
__global__ void self_init_kernel(const float* __restrict__ xw, const float* __restrict__ dinv,
                                 float* __restrict__ out, int n64) {
    int i = blockIdx.x * blockDim.x + threadIdx.x;
    if (i < n64) {
        float di = dinv[i >> 6];
        out[i] = xw[i] * di * di;
    }
}

// ---- GCN edge scatter: out[dst] += xw[src] * dinv[src]*dinv[dst] -----------
// one wave (64 lanes) per edge, lane = feature
__global__ __launch_bounds__(256) void gcn_scatter_kernel(const float* __restrict__ xw,
                                                          const float* __restrict__ dinv,
                                                          const int* __restrict__ src,
                                                          const int* __restrict__ dst,
                                                          float* __restrict__ out, int e) {
    int eid = (blockIdx.x * blockDim.x + threadIdx.x) >> 6;
    int j   = threadIdx.x & 63;
    if (eid < e) {
        int s = src[eid], d = dst[eid];
        float c = dinv[s] * dinv[d];
        atomicAdd(&out[d * D + j], xw[s * D + j] * c);
    }
}

// ---- x[i][j] = act(x[i][j] + b[j]) -----------------------------------------
__global__ void bias_act_kernel(float* __restrict__ x, const float* __restrict__ b,
                                int n64, int relu) {
    int i = blockIdx.x * blockDim.x + threadIdx.x;
    if (i < n64) {
        float v = x[i] + b[i & 63];
        x[i] = relu ? fmaxf(v, 0.0f) : v;
    }
}

// ---- attention logits: ev[e] = dot(q[dst], k[src]) / 8; segment max --------
__global__ __launch_bounds__(256) void logits_kernel(const float* __restrict__ q,
                                                     const float* __restrict__ k,
                                                     const int* __restrict__ src,
                                                     const int* __restrict__ dst,
                                                     float* __restrict__ ev,
                                                     int* __restrict__ mmax, int e) {
    int eid = (blockIdx.x * blockDim.x + threadIdx.x) >> 6;
    int j   = threadIdx.x & 63;
    if (eid >= e) return;
    int s = src[eid], d = dst[eid];
    float p = q[d * D + j] * k[s * D + j];
    #pragma unroll
    for (int off = 32; off; off >>= 1) p += __shfl_xor(p, off, 64);
    if (j == 0) {
        float logit = p * 0.125f;   // rsqrt(64)
        ev[eid] = logit;
        int im = __float_as_int(logit);
        im = (im >= 0) ? im : (im ^ 0x7FFFFFFF);   // monotone int mapping
        atomicMax(&mmax[d], im);
    }
}

// ---- ev[e] = exp(logit - m[dst]); z[dst] += ev[e] --------------------------
__global__ void expz_kernel(float* __restrict__ ev, const int* __restrict__ mmax,
                            const int* __restrict__ dst, float* __restrict__ z, int e) {
    int i = blockIdx.x * blockDim.x + threadIdx.x;
    if (i < e) {
        int d = dst[i];
        int im = mmax[d];
        im = (im >= 0) ? im : (im ^ 0x7FFFFFFF);   // inverse mapping (same op)
        float m = __int_as_float(im);
        float t = __expf(ev[i] - m);
        ev[i] = t;
        atomicAdd(&z[d], t);
    }
}

// ---- x2[dst] += v[src] * (ev[e] / z[dst]) ----------------------------------
__global__ __launch_bounds__(256) void aggr_kernel(const float* __restrict__ v,
                                                   const float* __restrict__ ev,
                                                   const float* __restrict__ z,
                                                   const int* __restrict__ src,
                                                   const int* __restrict__ dst,
                                                   float* __restrict__ x2, int e) {
    int eid = (blockIdx.x * blockDim.x + threadIdx.x) >> 6;
    int j   = threadIdx.x & 63;
    if (eid < e) {
        int s = src[eid], d = dst[eid];
        float alpha = ev[eid] / z[d];
        atomicAdd(&x2[d * D + j], v[s * D + j] * alpha);
    }
}

extern "C" void kernel_launch(void* const* d_in, const int* in_sizes, int n_in,
                              void* d_out, int out_size, void* d_ws, size_t ws_size,
                              hipStream_t stream) {
    const float* x  = (const float*)d_in[0];
    const int*   ei = (const int*)d_in[1];
    const float* W1 = (const float*)d_in[2];
    const float* b1 = (const float*)d_in[3];
    const float* Wq = (const float*)d_in[4];
    const float* bq = (const float*)d_in[5];
    const float* Wk = (const float*)d_in[6];
    const float* bk = (const float*)d_in[7];
    const float* Wv = (const float*)d_in[8];
    const float* bv = (const float*)d_in[9];
    const float* Ws = (const float*)d_in[10];
    const float* bs = (const float*)d_in[11];
    const float* W2 = (const float*)d_in[12];
    const float* b2 = (const float*)d_in[13];
    float* out = (float*)d_out;

    const int n = in_sizes[0] / D;   // 50000
    const int e = in_sizes[1] / 2;   // 800000
    const int* src = ei;
    const int* dst = ei + e;

    // workspace layout (floats): dinv[n] | mmax[n] | z[n] | ev[e] | 5 x [n*64]
    float* ws   = (float*)d_ws;
    float* dinv = ws;
    int*   mmax = (int*)(ws + n);
    float* z    = ws + 2 * (size_t)n;
    float* ev   = ws + 3 * (size_t)n;
    float* bufA = ws + 3 * (size_t)n + e;     // xw1, later q
    float* bufB = bufA + (size_t)n * D;       // x1, later xw2
    float* bufC = bufB + (size_t)n * D;       // k
    float* bufD = bufC + (size_t)n * D;       // v
    float* bufE = bufD + (size_t)n * D;       // x2

    const int n64   = n * D;
    const int nb_n  = (n + 255) / 256;
    const int nb_n64= (n64 + 255) / 256;
    const int nb_e  = (e + 255) / 256;
    const int nb_e64= (e + 3) / 4;            // wave-per-edge, 4 edges/block
    const int nb_g  = (n + 3) / 4;            // gemm: 4 rows/block

    // degrees -> dinv
    init_node_kernel<<<nb_n, 256, 0, stream>>>(dinv, mmax, z, n);
    deg_kernel<<<nb_e, 256, 0, stream>>>(dst, dinv, e);
    dinv_kernel<<<nb_n, 256, 0, stream>>>(dinv, n);

    // ---- GCN layer 1: x1 = relu(GCN(x)) ----
    gemm64_kernel<<<nb_g, 256, 0, stream>>>(x, W1, nullptr, bufA, n);       // xw1
    self_init_kernel<<<nb_n64, 256, 0, stream>>>(bufA, dinv, bufB, n64);
    gcn_scatter_kernel<<<nb_e64, 256, 0, stream>>>(bufA, dinv, src, dst, bufB, e);
    bias_act_kernel<<<nb_n64, 256, 0, stream>>>(bufB, b1, n64, 1);          // x1

    // ---- TransformerConv ----
    gemm64_kernel<<<nb_g, 256, 0, stream>>>(bufB, Wq, bq, bufA, n);         // q (xw1 dead)
    gemm64_kernel<<<nb_g, 256, 0, stream>>>(bufB, Wk, bk, bufC, n);         // k
    gemm64_kernel<<<nb_g, 256, 0, stream>>>(bufB, Wv, bv, bufD, n);         // v
    gemm64_kernel<<<nb_g, 256, 0, stream>>>(bufB, Ws, bs, bufE, n);         // x2 = x1@Ws+bs
    logits_kernel<<<nb_e64, 256, 0, stream>>>(bufA, bufC, src, dst, ev, mmax, e);
    expz_kernel<<<nb_e, 256, 0, stream>>>(ev, mmax, dst, z, e);
    aggr_kernel<<<nb_e64, 256, 0, stream>>>(bufD, ev, z, src, dst, bufE, e); // x2 += attn

    // ---- GCN layer 2 -> out ----
    gemm64_kernel<<<nb_g, 256, 0, stream>>>(bufE, W2, nullptr, bufB, n);    // xw2 (x1 dead)
    self_init_kernel<<<nb_n64, 256, 0, stream>>>(bufB, dinv, out, n64);
    gcn_scatter_kernel<<<nb_e64, 256, 0, stream>>>(bufB, dinv, src, dst, out, e);
    bias_act_kernel<<<nb_n64, 256, 0, stream>>>(out, b2, n64, 0);
}

// Round 2
// 538.740 us; speedup vs baseline: 1.8858x; 1.8858x over previous
//
#include <hip/hip_runtime.h>
#include <math.h>

// ---------------------------------------------------------------------------
// GraphTransformer: GCNConv(64->64)+ReLU -> TransformerConv(h=1) -> GCNConv(64->64)
// N=50000, E=800000, D=64, fp32.
// Round 2: CSR (dst-sorted) built per launch; all edge passes are GATHERS
// (wave-per-node, lane-per-feature, register accumulate) — zero fp32 atomics.
// Attention fully fused with online softmax. Register-tiled 4x4 GEMM.
// ---------------------------------------------------------------------------

#define D 64

// ============================ CSR construction =============================

__global__ void zero_int_kernel(int* __restrict__ p, int n) {
    int i = blockIdx.x * blockDim.x + threadIdx.x;
    if (i < n) p[i] = 0;
}

__global__ void hist_kernel(const int* __restrict__ dst, int* __restrict__ cnt, int e) {
    int i = blockIdx.x * blockDim.x + threadIdx.x;
    if (i < e) atomicAdd(&cnt[dst[i]], 1);
}

// dinv[i] = rsqrt(cnt[i] + 1)   (self-loop adds 1)
__global__ void dinv_kernel(const int* __restrict__ cnt, float* __restrict__ dinv, int n) {
    int i = blockIdx.x * blockDim.x + threadIdx.x;
    if (i < n) dinv[i] = rsqrtf((float)cnt[i] + 1.0f);
}

// block-level exclusive scan (256/block) + block totals
__global__ __launch_bounds__(256) void scan1_kernel(const int* __restrict__ cnt,
                                                    int* __restrict__ rowptr,
                                                    int* __restrict__ partials, int n) {
    __shared__ int sd[256];
    int t = threadIdx.x, g = blockIdx.x * 256 + t;
    int v = (g < n) ? cnt[g] : 0;
    sd[t] = v;
    __syncthreads();
    for (int off = 1; off < 256; off <<= 1) {
        int add = (t >= off) ? sd[t - off] : 0;
        __syncthreads();
        sd[t] += add;
        __syncthreads();
    }
    if (g < n) rowptr[g] = sd[t] - v;       // exclusive
    if (t == 255) partials[blockIdx.x] = sd[t];
}

// exclusive scan of block totals (nb <= 256, single block)
__global__ __launch_bounds__(256) void scan2_kernel(int* __restrict__ partials, int nb) {
    __shared__ int sd[256];
    int t = threadIdx.x;
    int v = (t < nb) ? partials[t] : 0;
    sd[t] = v;
    __syncthreads();
    for (int off = 1; off < 256; off <<= 1) {
        int add = (t >= off) ? sd[t - off] : 0;
        __syncthreads();
        sd[t] += add;
        __syncthreads();
    }
    if (t < nb) partials[t] = sd[t] - v;    // exclusive
}

__global__ void scan3_kernel(int* __restrict__ rowptr, const int* __restrict__ partials,
                             int* __restrict__ cursor, int n) {
    int g = blockIdx.x * 256 + threadIdx.x;
    if (g < n) {
        int r = rowptr[g] + partials[blockIdx.x];
        rowptr[g] = r;
        cursor[g] = r;
    }
}

__global__ void csr_scatter_kernel(const int* __restrict__ src, const int* __restrict__ dst,
                                   int* __restrict__ cursor, int* __restrict__ esrc, int e) {
    int i = blockIdx.x * blockDim.x + threadIdx.x;
    if (i < e) {
        int pos = atomicAdd(&cursor[dst[i]], 1);
        esrc[pos] = src[i];
    }
}

// ========================= register-tiled GEMM 64x64 =======================
// Y[n,64] = X[n,64] @ W[64,64] (+ bias). 64 rows/block, 256 threads,
// each thread computes a 4x4 tile. W and X staged in LDS; float4 W reads.
__global__ __launch_bounds__(256) void gemm64_fast(const float* __restrict__ X,
                                                   const float* __restrict__ W,
                                                   const float* __restrict__ bias,
                                                   float* __restrict__ Y, int n) {
    __shared__ float sX[64][65];   // +1 pad: rg-distinct banks
    __shared__ float sW[64 * 64];
    int t = threadIdx.x;
    int base = blockIdx.x * 64;
    #pragma unroll
    for (int i = 0; i < 16; ++i) sW[t + 256 * i] = W[t + 256 * i];
    #pragma unroll
    for (int i = 0; i < 16; ++i) {
        int idx = t + 256 * i;
        int r = idx >> 6, c = idx & 63;
        int row = base + r;
        sX[r][c] = (row < n) ? X[row * D + c] : 0.0f;
    }
    __syncthreads();

    int cg = t & 15, rg = t >> 4;
    int j0 = cg * 4, r0 = rg * 4;
    float acc[4][4];
    #pragma unroll
    for (int a = 0; a < 4; ++a)
        #pragma unroll
        for (int b = 0; b < 4; ++b) acc[a][b] = 0.0f;

    #pragma unroll 8
    for (int k = 0; k < 64; ++k) {
        float4 w = *(const float4*)&sW[k * 64 + j0];
        float x0 = sX[r0 + 0][k];
        float x1 = sX[r0 + 1][k];
        float x2 = sX[r0 + 2][k];
        float x3 = sX[r0 + 3][k];
        acc[0][0] = fmaf(x0, w.x, acc[0][0]); acc[0][1] = fmaf(x0, w.y, acc[0][1]);
        acc[0][2] = fmaf(x0, w.z, acc[0][2]); acc[0][3] = fmaf(x0, w.w, acc[0][3]);
        acc[1][0] = fmaf(x1, w.x, acc[1][0]); acc[1][1] = fmaf(x1, w.y, acc[1][1]);
        acc[1][2] = fmaf(x1, w.z, acc[1][2]); acc[1][3] = fmaf(x1, w.w, acc[1][3]);
        acc[2][0] = fmaf(x2, w.x, acc[2][0]); acc[2][1] = fmaf(x2, w.y, acc[2][1]);
        acc[2][2] = fmaf(x2, w.z, acc[2][2]); acc[2][3] = fmaf(x2, w.w, acc[2][3]);
        acc[3][0] = fmaf(x3, w.x, acc[3][0]); acc[3][1] = fmaf(x3, w.y, acc[3][1]);
        acc[3][2] = fmaf(x3, w.z, acc[3][2]); acc[3][3] = fmaf(x3, w.w, acc[3][3]);
    }

    float4 bb = make_float4(0.f, 0.f, 0.f, 0.f);
    if (bias) bb = *(const float4*)&bias[j0];
    #pragma unroll
    for (int a = 0; a < 4; ++a) {
        int row = base + r0 + a;
        if (row < n) {
            float4 o = make_float4(acc[a][0] + bb.x, acc[a][1] + bb.y,
                                   acc[a][2] + bb.z, acc[a][3] + bb.w);
            *(float4*)&Y[row * D + j0] = o;
        }
    }
}

// ============================ GCN gather ===================================
// out[d][j] = act( xw[d][j]*dinv[d]^2 + sum_{s in in(d)} xw[s][j]*dinv[s]*dinv[d] + b[j] )
// one wave per node, lane = feature; register accumulate, single store.
__global__ __launch_bounds__(256) void gcn_gather_kernel(const float* __restrict__ xw,
                                                         const float* __restrict__ dinv,
                                                         const int* __restrict__ rowptr,
                                                         const int* __restrict__ cnt,
                                                         const int* __restrict__ esrc,
                                                         const float* __restrict__ bias,
                                                         float* __restrict__ out,
                                                         int n, int relu) {
    int node = (blockIdx.x * blockDim.x + threadIdx.x) >> 6;
    int j = threadIdx.x & 63;
    if (node >= n) return;
    float dd = dinv[node];
    float acc = xw[node * D + j] * dd * dd;
    int start = rowptr[node], deg = cnt[node];
    for (int i = 0; i < deg; ++i) {
        int s = esrc[start + i];
        acc = fmaf(xw[s * D + j], dinv[s] * dd, acc);
    }
    float v = acc + bias[j];
    out[node * D + j] = relu ? fmaxf(v, 0.0f) : v;
}

// ===================== fused attention gather (online softmax) =============
// out[d] = skip[d] + sum_s softmax_s( dot(q[d],k[s])/8 ) * v[s]
__global__ __launch_bounds__(256) void attn_gather_kernel(const float* __restrict__ q,
                                                          const float* __restrict__ k,
                                                          const float* __restrict__ v,
                                                          const float* __restrict__ skip,
                                                          const int* __restrict__ rowptr,
                                                          const int* __restrict__ cnt,
                                                          const int* __restrict__ esrc,
                                                          float* __restrict__ out, int n) {
    int node = (blockIdx.x * blockDim.x + threadIdx.x) >> 6;
    int j = threadIdx.x & 63;
    if (node >= n) return;
    float qj = q[node * D + j];
    float m = -INFINITY, z = 0.0f, acc = 0.0f;
    int start = rowptr[node], deg = cnt[node];
    for (int i = 0; i < deg; ++i) {
        int s = esrc[start + i];
        float p = qj * k[s * D + j];
        #pragma unroll
        for (int off = 32; off; off >>= 1) p += __shfl_xor(p, off, 64);
        float l = p * 0.125f;                 // * rsqrt(64)
        float mn = fmaxf(m, l);
        float corr = __expf(m - mn);          // first iter: exp(-inf)=0
        float w = __expf(l - mn);
        z = z * corr + w;
        acc = fmaf(w, v[s * D + j], acc * corr);
        m = mn;
    }
    float r = skip[node * D + j];
    if (deg > 0) r += acc / z;
    out[node * D + j] = r;
}

// =============================== launch ====================================

extern "C" void kernel_launch(void* const* d_in, const int* in_sizes, int n_in,
                              void* d_out, int out_size, void* d_ws, size_t ws_size,
                              hipStream_t stream) {
    const float* x  = (const float*)d_in[0];
    const int*   ei = (const int*)d_in[1];
    const float* W1 = (const float*)d_in[2];
    const float* b1 = (const float*)d_in[3];
    const float* Wq = (const float*)d_in[4];
    const float* bq = (const float*)d_in[5];
    const float* Wk = (const float*)d_in[6];
    const float* bk = (const float*)d_in[7];
    const float* Wv = (const float*)d_in[8];
    const float* bv = (const float*)d_in[9];
    const float* Ws = (const float*)d_in[10];
    const float* bs = (const float*)d_in[11];
    const float* W2 = (const float*)d_in[12];
    const float* b2 = (const float*)d_in[13];
    float* out = (float*)d_out;

    const int n = in_sizes[0] / D;   // 50000
    const int e = in_sizes[1] / 2;   // 800000
    const int* src = ei;
    const int* dst = ei + e;
    const int n64 = n * D;

    // ---- workspace layout ----
    // ints: cnt[n] rowptr[n] cursor[n] partials[256] esrc[e]
    // floats: dinv[n] bufA bufB bufC bufD (n*64 each);  skip lives in d_out
    int* cnt      = (int*)d_ws;
    int* rowptr   = cnt + n;
    int* cursor   = rowptr + n;
    int* partials = cursor + n;
    int* esrc     = partials + 256;
    float* dinv   = (float*)(esrc + e);
    float* bufA   = dinv + n;
    float* bufB   = bufA + (size_t)n64;
    float* bufC   = bufB + (size_t)n64;
    float* bufD   = bufC + (size_t)n64;

    const int nb_n   = (n + 255) / 256;      // 196
    const int nb_e   = (e + 255) / 256;
    const int nb_nw  = (n + 3) / 4;          // wave-per-node, 4 nodes/block
    const int nb_g   = (n + 63) / 64;        // gemm: 64 rows/block

    // ---- CSR build ----
    zero_int_kernel<<<nb_n, 256, 0, stream>>>(cnt, n);
    hist_kernel<<<nb_e, 256, 0, stream>>>(dst, cnt, e);
    dinv_kernel<<<nb_n, 256, 0, stream>>>(cnt, dinv, n);
    scan1_kernel<<<nb_n, 256, 0, stream>>>(cnt, rowptr, partials, n);
    scan2_kernel<<<1, 256, 0, stream>>>(partials, nb_n);
    scan3_kernel<<<nb_n, 256, 0, stream>>>(rowptr, partials, cursor, n);
    csr_scatter_kernel<<<nb_e, 256, 0, stream>>>(src, dst, cursor, esrc, e);

    // ---- GCN layer 1: x1 = relu(GCN(x) + b1) ----
    gemm64_fast<<<nb_g, 256, 0, stream>>>(x, W1, nullptr, bufA, n);                 // xw1 -> A
    gcn_gather_kernel<<<nb_nw, 256, 0, stream>>>(bufA, dinv, rowptr, cnt, esrc,
                                                 b1, bufB, n, 1);                   // x1 -> B

    // ---- TransformerConv ----
    gemm64_fast<<<nb_g, 256, 0, stream>>>(bufB, Wq, bq, bufA, n);                   // q -> A
    gemm64_fast<<<nb_g, 256, 0, stream>>>(bufB, Wk, bk, bufC, n);                   // k -> C
    gemm64_fast<<<nb_g, 256, 0, stream>>>(bufB, Wv, bv, bufD, n);                   // v -> D
    gemm64_fast<<<nb_g, 256, 0, stream>>>(bufB, Ws, bs, out, n);                    // skip -> out
    attn_gather_kernel<<<nb_nw, 256, 0, stream>>>(bufA, bufC, bufD, out,
                                                  rowptr, cnt, esrc, bufB, n);      // x2 -> B

    // ---- GCN layer 2 -> out ----
    gemm64_fast<<<nb_g, 256, 0, stream>>>(bufB, W2, nullptr, bufC, n);              // xw2 -> C
    gcn_gather_kernel<<<nb_nw, 256, 0, stream>>>(bufC, dinv, rowptr, cnt, esrc,
                                                 b2, out, n, 0);
}

// Round 3
// 386.275 us; speedup vs baseline: 2.6301x; 1.3947x over previous
//
#include <hip/hip_runtime.h>
#include <math.h>

// ---------------------------------------------------------------------------
// GraphTransformer: GCNConv(64->64)+ReLU -> TransformerConv(h=1) -> GCNConv(64->64)
// N=50000, E=800000, D=64, fp32.
// Round 3: gather kernels restructured — wave = 1 node, split into 4 groups
// of 16 lanes (lane = 4 features via float4). Each group walks a strided
// quarter of the edge list (4 edges in flight per wave), partials merged by
// xor-butterfly. Online softmax per group for attention.
// ---------------------------------------------------------------------------

#define D 64

// ============================ CSR construction =============================

__global__ void zero_int_kernel(int* __restrict__ p, int n) {
    int i = blockIdx.x * blockDim.x + threadIdx.x;
    if (i < n) p[i] = 0;
}

__global__ void hist_kernel(const int* __restrict__ dst, int* __restrict__ cnt, int e) {
    int i = blockIdx.x * blockDim.x + threadIdx.x;
    if (i < e) atomicAdd(&cnt[dst[i]], 1);
}

__global__ void dinv_kernel(const int* __restrict__ cnt, float* __restrict__ dinv, int n) {
    int i = blockIdx.x * blockDim.x + threadIdx.x;
    if (i < n) dinv[i] = rsqrtf((float)cnt[i] + 1.0f);   // +1: self-loop
}

__global__ __launch_bounds__(256) void scan1_kernel(const int* __restrict__ cnt,
                                                    int* __restrict__ rowptr,
                                                    int* __restrict__ partials, int n) {
    __shared__ int sd[256];
    int t = threadIdx.x, g = blockIdx.x * 256 + t;
    int v = (g < n) ? cnt[g] : 0;
    sd[t] = v;
    __syncthreads();
    for (int off = 1; off < 256; off <<= 1) {
        int add = (t >= off) ? sd[t - off] : 0;
        __syncthreads();
        sd[t] += add;
        __syncthreads();
    }
    if (g < n) rowptr[g] = sd[t] - v;       // exclusive
    if (t == 255) partials[blockIdx.x] = sd[t];
}

__global__ __launch_bounds__(256) void scan2_kernel(int* __restrict__ partials, int nb) {
    __shared__ int sd[256];
    int t = threadIdx.x;
    int v = (t < nb) ? partials[t] : 0;
    sd[t] = v;
    __syncthreads();
    for (int off = 1; off < 256; off <<= 1) {
        int add = (t >= off) ? sd[t - off] : 0;
        __syncthreads();
        sd[t] += add;
        __syncthreads();
    }
    if (t < nb) partials[t] = sd[t] - v;    // exclusive
}

__global__ void scan3_kernel(int* __restrict__ rowptr, const int* __restrict__ partials,
                             int* __restrict__ cursor, int n) {
    int g = blockIdx.x * 256 + threadIdx.x;
    if (g < n) {
        int r = rowptr[g] + partials[blockIdx.x];
        rowptr[g] = r;
        cursor[g] = r;
    }
}

__global__ void csr_scatter_kernel(const int* __restrict__ src, const int* __restrict__ dst,
                                   int* __restrict__ cursor, int* __restrict__ esrc, int e) {
    int i = blockIdx.x * blockDim.x + threadIdx.x;
    if (i < e) {
        int pos = atomicAdd(&cursor[dst[i]], 1);
        esrc[pos] = src[i];
    }
}

// ========================= register-tiled GEMM 64x64 =======================
__global__ __launch_bounds__(256) void gemm64_fast(const float* __restrict__ X,
                                                   const float* __restrict__ W,
                                                   const float* __restrict__ bias,
                                                   float* __restrict__ Y, int n) {
    __shared__ float sX[64][65];
    __shared__ float sW[64 * 64];
    int t = threadIdx.x;
    int base = blockIdx.x * 64;
    #pragma unroll
    for (int i = 0; i < 16; ++i) sW[t + 256 * i] = W[t + 256 * i];
    #pragma unroll
    for (int i = 0; i < 16; ++i) {
        int idx = t + 256 * i;
        int r = idx >> 6, c = idx & 63;
        int row = base + r;
        sX[r][c] = (row < n) ? X[row * D + c] : 0.0f;
    }
    __syncthreads();

    int cg = t & 15, rg = t >> 4;
    int j0 = cg * 4, r0 = rg * 4;
    float acc[4][4];
    #pragma unroll
    for (int a = 0; a < 4; ++a)
        #pragma unroll
        for (int b = 0; b < 4; ++b) acc[a][b] = 0.0f;

    #pragma unroll 8
    for (int k = 0; k < 64; ++k) {
        float4 w = *(const float4*)&sW[k * 64 + j0];
        float x0 = sX[r0 + 0][k];
        float x1 = sX[r0 + 1][k];
        float x2 = sX[r0 + 2][k];
        float x3 = sX[r0 + 3][k];
        acc[0][0] = fmaf(x0, w.x, acc[0][0]); acc[0][1] = fmaf(x0, w.y, acc[0][1]);
        acc[0][2] = fmaf(x0, w.z, acc[0][2]); acc[0][3] = fmaf(x0, w.w, acc[0][3]);
        acc[1][0] = fmaf(x1, w.x, acc[1][0]); acc[1][1] = fmaf(x1, w.y, acc[1][1]);
        acc[1][2] = fmaf(x1, w.z, acc[1][2]); acc[1][3] = fmaf(x1, w.w, acc[1][3]);
        acc[2][0] = fmaf(x2, w.x, acc[2][0]); acc[2][1] = fmaf(x2, w.y, acc[2][1]);
        acc[2][2] = fmaf(x2, w.z, acc[2][2]); acc[2][3] = fmaf(x2, w.w, acc[2][3]);
        acc[3][0] = fmaf(x3, w.x, acc[3][0]); acc[3][1] = fmaf(x3, w.y, acc[3][1]);
        acc[3][2] = fmaf(x3, w.z, acc[3][2]); acc[3][3] = fmaf(x3, w.w, acc[3][3]);
    }

    float4 bb = make_float4(0.f, 0.f, 0.f, 0.f);
    if (bias) bb = *(const float4*)&bias[j0];
    #pragma unroll
    for (int a = 0; a < 4; ++a) {
        int row = base + r0 + a;
        if (row < n) {
            float4 o = make_float4(acc[a][0] + bb.x, acc[a][1] + bb.y,
                                   acc[a][2] + bb.z, acc[a][3] + bb.w);
            *(float4*)&Y[row * D + j0] = o;
        }
    }
}

// ============================ GCN gather (grouped) =========================
// wave = 1 node; 4 groups x 16 lanes; lane holds 4 features (float4).
// Group g walks edges g, g+4, g+8, ...; partial sums merged by butterfly.
__global__ __launch_bounds__(256) void gcn_gather_kernel(const float* __restrict__ xw,
                                                         const float* __restrict__ dinv,
                                                         const int* __restrict__ rowptr,
                                                         const int* __restrict__ cnt,
                                                         const int* __restrict__ esrc,
                                                         const float* __restrict__ bias,
                                                         float* __restrict__ out,
                                                         int n, int relu) {
    int node = (blockIdx.x * blockDim.x + threadIdx.x) >> 6;
    if (node >= n) return;
    int lane = threadIdx.x & 63;
    int grp = lane >> 4;          // 0..3
    int sub = lane & 15;          // 0..15 -> features sub*4..sub*4+3
    int j0 = sub * 4;

    float dd = dinv[node];
    int start = rowptr[node], deg = cnt[node];

    float4 acc = make_float4(0.f, 0.f, 0.f, 0.f);
    int i = grp;
    int sNext = (i < deg) ? esrc[start + i] : 0;
    for (; i < deg; i += 4) {
        int s = sNext;
        int in = i + 4;
        if (in < deg) sNext = esrc[start + in];
        float c = dinv[s] * dd;
        float4 xv = *(const float4*)&xw[s * D + j0];
        acc.x = fmaf(c, xv.x, acc.x);
        acc.y = fmaf(c, xv.y, acc.y);
        acc.z = fmaf(c, xv.z, acc.z);
        acc.w = fmaf(c, xv.w, acc.w);
    }
    // merge the 4 group partials (butterfly over lanes ^16, ^32)
    acc.x += __shfl_xor(acc.x, 16, 64); acc.x += __shfl_xor(acc.x, 32, 64);
    acc.y += __shfl_xor(acc.y, 16, 64); acc.y += __shfl_xor(acc.y, 32, 64);
    acc.z += __shfl_xor(acc.z, 16, 64); acc.z += __shfl_xor(acc.z, 32, 64);
    acc.w += __shfl_xor(acc.w, 16, 64); acc.w += __shfl_xor(acc.w, 32, 64);

    if (grp == 0) {
        float4 self = *(const float4*)&xw[node * D + j0];
        float4 b = *(const float4*)&bias[j0];
        float dd2 = dd * dd;
        float4 o;
        o.x = fmaf(self.x, dd2, acc.x) + b.x;
        o.y = fmaf(self.y, dd2, acc.y) + b.y;
        o.z = fmaf(self.z, dd2, acc.z) + b.z;
        o.w = fmaf(self.w, dd2, acc.w) + b.w;
        if (relu) {
            o.x = fmaxf(o.x, 0.f); o.y = fmaxf(o.y, 0.f);
            o.z = fmaxf(o.z, 0.f); o.w = fmaxf(o.w, 0.f);
        }
        *(float4*)&out[node * D + j0] = o;
    }
}

// ===================== fused attention gather (grouped online softmax) =====
// out[d] = skip[d] + sum_s softmax_s( dot(q[d],k[s])/8 ) * v[s]
__global__ __launch_bounds__(256) void attn_gather_kernel(const float* __restrict__ q,
                                                          const float* __restrict__ k,
                                                          const float* __restrict__ v,
                                                          const float* __restrict__ skip,
                                                          const int* __restrict__ rowptr,
                                                          const int* __restrict__ cnt,
                                                          const int* __restrict__ esrc,
                                                          float* __restrict__ out, int n) {
    int node = (blockIdx.x * blockDim.x + threadIdx.x) >> 6;
    if (node >= n) return;
    int lane = threadIdx.x & 63;
    int grp = lane >> 4;
    int sub = lane & 15;
    int j0 = sub * 4;

    int start = rowptr[node], deg = cnt[node];
    float4 q4 = *(const float4*)&q[node * D + j0];

    float m = -INFINITY, z = 0.0f;
    float4 acc = make_float4(0.f, 0.f, 0.f, 0.f);

    int i = grp;
    int sNext = (i < deg) ? esrc[start + i] : 0;
    for (; i < deg; i += 4) {
        int s = sNext;
        int in = i + 4;
        if (in < deg) sNext = esrc[start + in];
        float4 k4 = *(const float4*)&k[s * D + j0];
        float p = q4.x * k4.x + q4.y * k4.y + q4.z * k4.z + q4.w * k4.w;
        // reduce across the 16 lanes of this group
        p += __shfl_xor(p, 1, 64);
        p += __shfl_xor(p, 2, 64);
        p += __shfl_xor(p, 4, 64);
        p += __shfl_xor(p, 8, 64);
        float l = p * 0.125f;                  // * rsqrt(64)
        float mn = fmaxf(m, l);
        float corr = __expf(m - mn);           // first edge: exp(-inf)=0
        float w = __expf(l - mn);
        float4 v4 = *(const float4*)&v[s * D + j0];
        z = z * corr + w;
        acc.x = fmaf(w, v4.x, acc.x * corr);
        acc.y = fmaf(w, v4.y, acc.y * corr);
        acc.z = fmaf(w, v4.z, acc.z * corr);
        acc.w = fmaf(w, v4.w, acc.w * corr);
        m = mn;
    }

    if (deg > 0) {
        // merge 4 group softmax states: M = max m_g; z,acc rescaled by exp(m_g-M)
        float m1 = fmaxf(m, __shfl_xor(m, 16, 64));
        float M  = fmaxf(m1, __shfl_xor(m1, 32, 64));
        float sc = __expf(m - M);              // empty group: exp(-inf-M)=0
        float zs = z * sc;
        zs += __shfl_xor(zs, 16, 64);
        zs += __shfl_xor(zs, 32, 64);
        acc.x *= sc; acc.y *= sc; acc.z *= sc; acc.w *= sc;
        acc.x += __shfl_xor(acc.x, 16, 64); acc.x += __shfl_xor(acc.x, 32, 64);
        acc.y += __shfl_xor(acc.y, 16, 64); acc.y += __shfl_xor(acc.y, 32, 64);
        acc.z += __shfl_xor(acc.z, 16, 64); acc.z += __shfl_xor(acc.z, 32, 64);
        acc.w += __shfl_xor(acc.w, 16, 64); acc.w += __shfl_xor(acc.w, 32, 64);
        if (grp == 0) {
            float inv = 1.0f / zs;
            float4 sk = *(const float4*)&skip[node * D + j0];
            float4 o;
            o.x = fmaf(acc.x, inv, sk.x);
            o.y = fmaf(acc.y, inv, sk.y);
            o.z = fmaf(acc.z, inv, sk.z);
            o.w = fmaf(acc.w, inv, sk.w);
            *(float4*)&out[node * D + j0] = o;
        }
    } else if (grp == 0) {
        float4 sk = *(const float4*)&skip[node * D + j0];
        *(float4*)&out[node * D + j0] = sk;
    }
}

// =============================== launch ====================================

extern "C" void kernel_launch(void* const* d_in, const int* in_sizes, int n_in,
                              void* d_out, int out_size, void* d_ws, size_t ws_size,
                              hipStream_t stream) {
    const float* x  = (const float*)d_in[0];
    const int*   ei = (const int*)d_in[1];
    const float* W1 = (const float*)d_in[2];
    const float* b1 = (const float*)d_in[3];
    const float* Wq = (const float*)d_in[4];
    const float* bq = (const float*)d_in[5];
    const float* Wk = (const float*)d_in[6];
    const float* bk = (const float*)d_in[7];
    const float* Wv = (const float*)d_in[8];
    const float* bv = (const float*)d_in[9];
    const float* Ws = (const float*)d_in[10];
    const float* bs = (const float*)d_in[11];
    const float* W2 = (const float*)d_in[12];
    const float* b2 = (const float*)d_in[13];
    float* out = (float*)d_out;

    const int n = in_sizes[0] / D;   // 50000
    const int e = in_sizes[1] / 2;   // 800000
    const int* src = ei;
    const int* dst = ei + e;
    const int n64 = n * D;

    int* cnt      = (int*)d_ws;
    int* rowptr   = cnt + n;
    int* cursor   = rowptr + n;
    int* partials = cursor + n;
    int* esrc     = partials + 256;
    float* dinv   = (float*)(esrc + e);
    float* bufA   = dinv + n;
    float* bufB   = bufA + (size_t)n64;
    float* bufC   = bufB + (size_t)n64;
    float* bufD   = bufC + (size_t)n64;

    const int nb_n   = (n + 255) / 256;      // 196
    const int nb_e   = (e + 255) / 256;
    const int nb_nw  = (n + 3) / 4;          // wave-per-node, 4 nodes/block
    const int nb_g   = (n + 63) / 64;        // gemm: 64 rows/block

    // ---- CSR build ----
    zero_int_kernel<<<nb_n, 256, 0, stream>>>(cnt, n);
    hist_kernel<<<nb_e, 256, 0, stream>>>(dst, cnt, e);
    dinv_kernel<<<nb_n, 256, 0, stream>>>(cnt, dinv, n);
    scan1_kernel<<<nb_n, 256, 0, stream>>>(cnt, rowptr, partials, n);
    scan2_kernel<<<1, 256, 0, stream>>>(partials, nb_n);
    scan3_kernel<<<nb_n, 256, 0, stream>>>(rowptr, partials, cursor, n);
    csr_scatter_kernel<<<nb_e, 256, 0, stream>>>(src, dst, cursor, esrc, e);

    // ---- GCN layer 1: x1 = relu(GCN(x) + b1) ----
    gemm64_fast<<<nb_g, 256, 0, stream>>>(x, W1, nullptr, bufA, n);                 // xw1 -> A
    gcn_gather_kernel<<<nb_nw, 256, 0, stream>>>(bufA, dinv, rowptr, cnt, esrc,
                                                 b1, bufB, n, 1);                   // x1 -> B

    // ---- TransformerConv ----
    gemm64_fast<<<nb_g, 256, 0, stream>>>(bufB, Wq, bq, bufA, n);                   // q -> A
    gemm64_fast<<<nb_g, 256, 0, stream>>>(bufB, Wk, bk, bufC, n);                   // k -> C
    gemm64_fast<<<nb_g, 256, 0, stream>>>(bufB, Wv, bv, bufD, n);                   // v -> D
    gemm64_fast<<<nb_g, 256, 0, stream>>>(bufB, Ws, bs, out, n);                    // skip -> out
    attn_gather_kernel<<<nb_nw, 256, 0, stream>>>(bufA, bufC, bufD, out,
                                                  rowptr, cnt, esrc, bufB, n);      // x2 -> B

    // ---- GCN layer 2 -> out ----
    gemm64_fast<<<nb_g, 256, 0, stream>>>(bufB, W2, nullptr, bufC, n);              // xw2 -> C
    gcn_gather_kernel<<<nb_nw, 256, 0, stream>>>(bufC, dinv, rowptr, cnt, esrc,
                                                 b2, out, n, 0);
}

// Round 4
// 363.847 us; speedup vs baseline: 2.7922x; 1.0616x over previous
//
#include <hip/hip_runtime.h>
#include <math.h>

// ---------------------------------------------------------------------------
// GraphTransformer: GCNConv(64->64)+ReLU -> TransformerConv(h=1) -> GCNConv(64->64)
// N=50000, E=800000, D=64, fp32.
// Round 4: gathers use 8 groups x 8 lanes per wave (lane = 8 features via
// 2x float4) -> 8 edges in flight, ~2-3 serial iterations per node.
// Q/K/V/skip GEMMs fused into one kernel (x1 staged in LDS once).
// ---------------------------------------------------------------------------

#define D 64

// ============================ CSR construction =============================

__global__ void zero_int_kernel(int* __restrict__ p, int n) {
    int i = blockIdx.x * blockDim.x + threadIdx.x;
    if (i < n) p[i] = 0;
}

__global__ void hist_kernel(const int* __restrict__ dst, int* __restrict__ cnt, int e) {
    int i = blockIdx.x * blockDim.x + threadIdx.x;
    if (i < e) atomicAdd(&cnt[dst[i]], 1);
}

// scan1 also emits dinv[i] = rsqrt(cnt[i]+1) (self-loop)
__global__ __launch_bounds__(256) void scan1_kernel(const int* __restrict__ cnt,
                                                    int* __restrict__ rowptr,
                                                    int* __restrict__ partials,
                                                    float* __restrict__ dinv, int n) {
    __shared__ int sd[256];
    int t = threadIdx.x, g = blockIdx.x * 256 + t;
    int v = (g < n) ? cnt[g] : 0;
    if (g < n) dinv[g] = rsqrtf((float)v + 1.0f);
    sd[t] = v;
    __syncthreads();
    for (int off = 1; off < 256; off <<= 1) {
        int add = (t >= off) ? sd[t - off] : 0;
        __syncthreads();
        sd[t] += add;
        __syncthreads();
    }
    if (g < n) rowptr[g] = sd[t] - v;       // exclusive
    if (t == 255) partials[blockIdx.x] = sd[t];
}

__global__ __launch_bounds__(256) void scan2_kernel(int* __restrict__ partials, int nb) {
    __shared__ int sd[256];
    int t = threadIdx.x;
    int v = (t < nb) ? partials[t] : 0;
    sd[t] = v;
    __syncthreads();
    for (int off = 1; off < 256; off <<= 1) {
        int add = (t >= off) ? sd[t - off] : 0;
        __syncthreads();
        sd[t] += add;
        __syncthreads();
    }
    if (t < nb) partials[t] = sd[t] - v;    // exclusive
}

__global__ void scan3_kernel(int* __restrict__ rowptr, const int* __restrict__ partials,
                             int* __restrict__ cursor, int n) {
    int g = blockIdx.x * 256 + threadIdx.x;
    if (g < n) {
        int r = rowptr[g] + partials[blockIdx.x];
        rowptr[g] = r;
        cursor[g] = r;
    }
}

__global__ void csr_scatter_kernel(const int* __restrict__ src, const int* __restrict__ dst,
                                   int* __restrict__ cursor, int* __restrict__ esrc, int e) {
    int i = blockIdx.x * blockDim.x + threadIdx.x;
    if (i < e) {
        int pos = atomicAdd(&cursor[dst[i]], 1);
        esrc[pos] = src[i];
    }
}

// ========================= register-tiled GEMM 64x64 =======================
__global__ __launch_bounds__(256) void gemm64_fast(const float* __restrict__ X,
                                                   const float* __restrict__ W,
                                                   const float* __restrict__ bias,
                                                   float* __restrict__ Y, int n) {
    __shared__ float sX[64][65];
    __shared__ float sW[64 * 64];
    int t = threadIdx.x;
    int base = blockIdx.x * 64;
    #pragma unroll
    for (int i = 0; i < 16; ++i) sW[t + 256 * i] = W[t + 256 * i];
    #pragma unroll
    for (int i = 0; i < 16; ++i) {
        int idx = t + 256 * i;
        int r = idx >> 6, c = idx & 63;
        int row = base + r;
        sX[r][c] = (row < n) ? X[row * D + c] : 0.0f;
    }
    __syncthreads();

    int cg = t & 15, rg = t >> 4;
    int j0 = cg * 4, r0 = rg * 4;
    float acc[4][4];
    #pragma unroll
    for (int a = 0; a < 4; ++a)
        #pragma unroll
        for (int b = 0; b < 4; ++b) acc[a][b] = 0.0f;

    #pragma unroll 8
    for (int k = 0; k < 64; ++k) {
        float4 w = *(const float4*)&sW[k * 64 + j0];
        float x0 = sX[r0 + 0][k];
        float x1 = sX[r0 + 1][k];
        float x2 = sX[r0 + 2][k];
        float x3 = sX[r0 + 3][k];
        acc[0][0] = fmaf(x0, w.x, acc[0][0]); acc[0][1] = fmaf(x0, w.y, acc[0][1]);
        acc[0][2] = fmaf(x0, w.z, acc[0][2]); acc[0][3] = fmaf(x0, w.w, acc[0][3]);
        acc[1][0] = fmaf(x1, w.x, acc[1][0]); acc[1][1] = fmaf(x1, w.y, acc[1][1]);
        acc[1][2] = fmaf(x1, w.z, acc[1][2]); acc[1][3] = fmaf(x1, w.w, acc[1][3]);
        acc[2][0] = fmaf(x2, w.x, acc[2][0]); acc[2][1] = fmaf(x2, w.y, acc[2][1]);
        acc[2][2] = fmaf(x2, w.z, acc[2][2]); acc[2][3] = fmaf(x2, w.w, acc[2][3]);
        acc[3][0] = fmaf(x3, w.x, acc[3][0]); acc[3][1] = fmaf(x3, w.y, acc[3][1]);
        acc[3][2] = fmaf(x3, w.z, acc[3][2]); acc[3][3] = fmaf(x3, w.w, acc[3][3]);
    }

    float4 bb = make_float4(0.f, 0.f, 0.f, 0.f);
    if (bias) bb = *(const float4*)&bias[j0];
    #pragma unroll
    for (int a = 0; a < 4; ++a) {
        int row = base + r0 + a;
        if (row < n) {
            float4 o = make_float4(acc[a][0] + bb.x, acc[a][1] + bb.y,
                                   acc[a][2] + bb.z, acc[a][3] + bb.w);
            *(float4*)&Y[row * D + j0] = o;
        }
    }
}

// ================== fused QKVS GEMM: 4 weight mats, X staged once ==========
__global__ __launch_bounds__(256) void gemm_qkvs(const float* __restrict__ X,
                                                 const float* __restrict__ Wq,
                                                 const float* __restrict__ bq,
                                                 const float* __restrict__ Wk,
                                                 const float* __restrict__ bk,
                                                 const float* __restrict__ Wv,
                                                 const float* __restrict__ bv,
                                                 const float* __restrict__ Ws,
                                                 const float* __restrict__ bs,
                                                 float* __restrict__ Yq,
                                                 float* __restrict__ Yk,
                                                 float* __restrict__ Yv,
                                                 float* __restrict__ Ys, int n) {
    __shared__ float sX[64][65];
    __shared__ float sW[64 * 64];
    int t = threadIdx.x;
    int base = blockIdx.x * 64;
    #pragma unroll
    for (int i = 0; i < 16; ++i) {
        int idx = t + 256 * i;
        int r = idx >> 6, c = idx & 63;
        int row = base + r;
        sX[r][c] = (row < n) ? X[row * D + c] : 0.0f;
    }

    const float* Wl[4] = {Wq, Wk, Wv, Ws};
    const float* bl[4] = {bq, bk, bv, bs};
    float*       Yl[4] = {Yq, Yk, Yv, Ys};

    int cg = t & 15, rg = t >> 4;
    int j0 = cg * 4, r0 = rg * 4;

    #pragma unroll
    for (int w4 = 0; w4 < 4; ++w4) {
        const float* W = Wl[w4];
        __syncthreads();   // protect sW from previous iteration's readers
        #pragma unroll
        for (int i = 0; i < 16; ++i) sW[t + 256 * i] = W[t + 256 * i];
        __syncthreads();

        float acc[4][4];
        #pragma unroll
        for (int a = 0; a < 4; ++a)
            #pragma unroll
            for (int b = 0; b < 4; ++b) acc[a][b] = 0.0f;

        #pragma unroll 8
        for (int k = 0; k < 64; ++k) {
            float4 w = *(const float4*)&sW[k * 64 + j0];
            float x0 = sX[r0 + 0][k];
            float x1 = sX[r0 + 1][k];
            float x2 = sX[r0 + 2][k];
            float x3 = sX[r0 + 3][k];
            acc[0][0] = fmaf(x0, w.x, acc[0][0]); acc[0][1] = fmaf(x0, w.y, acc[0][1]);
            acc[0][2] = fmaf(x0, w.z, acc[0][2]); acc[0][3] = fmaf(x0, w.w, acc[0][3]);
            acc[1][0] = fmaf(x1, w.x, acc[1][0]); acc[1][1] = fmaf(x1, w.y, acc[1][1]);
            acc[1][2] = fmaf(x1, w.z, acc[1][2]); acc[1][3] = fmaf(x1, w.w, acc[1][3]);
            acc[2][0] = fmaf(x2, w.x, acc[2][0]); acc[2][1] = fmaf(x2, w.y, acc[2][1]);
            acc[2][2] = fmaf(x2, w.z, acc[2][2]); acc[2][3] = fmaf(x2, w.w, acc[2][3]);
            acc[3][0] = fmaf(x3, w.x, acc[3][0]); acc[3][1] = fmaf(x3, w.y, acc[3][1]);
            acc[3][2] = fmaf(x3, w.z, acc[3][2]); acc[3][3] = fmaf(x3, w.w, acc[3][3]);
        }

        float4 bb = *(const float4*)&bl[w4][j0];
        float* Y = Yl[w4];
        #pragma unroll
        for (int a = 0; a < 4; ++a) {
            int row = base + r0 + a;
            if (row < n) {
                float4 o = make_float4(acc[a][0] + bb.x, acc[a][1] + bb.y,
                                       acc[a][2] + bb.z, acc[a][3] + bb.w);
                *(float4*)&Y[row * D + j0] = o;
            }
        }
    }
}

// ============================ GCN gather (8x8 grouped) =====================
// wave = 1 node; 8 groups x 8 lanes; lane holds 8 features (2x float4).
__global__ __launch_bounds__(256) void gcn_gather_kernel(const float* __restrict__ xw,
                                                         const float* __restrict__ dinv,
                                                         const int* __restrict__ rowptr,
                                                         const int* __restrict__ cnt,
                                                         const int* __restrict__ esrc,
                                                         const float* __restrict__ bias,
                                                         float* __restrict__ out,
                                                         int n, int relu) {
    int node = (blockIdx.x * blockDim.x + threadIdx.x) >> 6;
    if (node >= n) return;
    int lane = threadIdx.x & 63;
    int grp = lane >> 3;          // 0..7
    int sub = lane & 7;           // features sub*8 .. sub*8+7
    int j0 = sub * 8;

    float dd = dinv[node];
    int start = rowptr[node], deg = cnt[node];

    float4 a0 = make_float4(0.f, 0.f, 0.f, 0.f);
    float4 a1 = make_float4(0.f, 0.f, 0.f, 0.f);
    int i = grp;
    int sNext = (i < deg) ? esrc[start + i] : 0;
    for (; i < deg; i += 8) {
        int s = sNext;
        int in = i + 8;
        if (in < deg) sNext = esrc[start + in];
        float c = dinv[s] * dd;
        float4 x0 = *(const float4*)&xw[s * D + j0];
        float4 x1 = *(const float4*)&xw[s * D + j0 + 4];
        a0.x = fmaf(c, x0.x, a0.x); a0.y = fmaf(c, x0.y, a0.y);
        a0.z = fmaf(c, x0.z, a0.z); a0.w = fmaf(c, x0.w, a0.w);
        a1.x = fmaf(c, x1.x, a1.x); a1.y = fmaf(c, x1.y, a1.y);
        a1.z = fmaf(c, x1.z, a1.z); a1.w = fmaf(c, x1.w, a1.w);
    }
    // merge 8 group partials: butterfly over lanes ^8, ^16, ^32
    #pragma unroll
    for (int off = 8; off < 64; off <<= 1) {
        a0.x += __shfl_xor(a0.x, off, 64); a0.y += __shfl_xor(a0.y, off, 64);
        a0.z += __shfl_xor(a0.z, off, 64); a0.w += __shfl_xor(a0.w, off, 64);
        a1.x += __shfl_xor(a1.x, off, 64); a1.y += __shfl_xor(a1.y, off, 64);
        a1.z += __shfl_xor(a1.z, off, 64); a1.w += __shfl_xor(a1.w, off, 64);
    }

    if (grp == 0) {
        float4 s0 = *(const float4*)&xw[node * D + j0];
        float4 s1 = *(const float4*)&xw[node * D + j0 + 4];
        float4 b0 = *(const float4*)&bias[j0];
        float4 b1 = *(const float4*)&bias[j0 + 4];
        float dd2 = dd * dd;
        float4 o0, o1;
        o0.x = fmaf(s0.x, dd2, a0.x) + b0.x;
        o0.y = fmaf(s0.y, dd2, a0.y) + b0.y;
        o0.z = fmaf(s0.z, dd2, a0.z) + b0.z;
        o0.w = fmaf(s0.w, dd2, a0.w) + b0.w;
        o1.x = fmaf(s1.x, dd2, a1.x) + b1.x;
        o1.y = fmaf(s1.y, dd2, a1.y) + b1.y;
        o1.z = fmaf(s1.z, dd2, a1.z) + b1.z;
        o1.w = fmaf(s1.w, dd2, a1.w) + b1.w;
        if (relu) {
            o0.x = fmaxf(o0.x, 0.f); o0.y = fmaxf(o0.y, 0.f);
            o0.z = fmaxf(o0.z, 0.f); o0.w = fmaxf(o0.w, 0.f);
            o1.x = fmaxf(o1.x, 0.f); o1.y = fmaxf(o1.y, 0.f);
            o1.z = fmaxf(o1.z, 0.f); o1.w = fmaxf(o1.w, 0.f);
        }
        *(float4*)&out[node * D + j0] = o0;
        *(float4*)&out[node * D + j0 + 4] = o1;
    }
}

// ===================== fused attention gather (8x8 online softmax) =========
__global__ __launch_bounds__(256) void attn_gather_kernel(const float* __restrict__ q,
                                                          const float* __restrict__ k,
                                                          const float* __restrict__ v,
                                                          const float* __restrict__ skip,
                                                          const int* __restrict__ rowptr,
                                                          const int* __restrict__ cnt,
                                                          const int* __restrict__ esrc,
                                                          float* __restrict__ out, int n) {
    int node = (blockIdx.x * blockDim.x + threadIdx.x) >> 6;
    if (node >= n) return;
    int lane = threadIdx.x & 63;
    int grp = lane >> 3;
    int sub = lane & 7;
    int j0 = sub * 8;

    int start = rowptr[node], deg = cnt[node];
    float4 q0 = *(const float4*)&q[node * D + j0];
    float4 q1 = *(const float4*)&q[node * D + j0 + 4];

    float m = -INFINITY, z = 0.0f;
    float4 a0 = make_float4(0.f, 0.f, 0.f, 0.f);
    float4 a1 = make_float4(0.f, 0.f, 0.f, 0.f);

    int i = grp;
    int sNext = (i < deg) ? esrc[start + i] : 0;
    for (; i < deg; i += 8) {
        int s = sNext;
        int in = i + 8;
        if (in < deg) sNext = esrc[start + in];
        float4 k0 = *(const float4*)&k[s * D + j0];
        float4 k1 = *(const float4*)&k[s * D + j0 + 4];
        float p = q0.x * k0.x + q0.y * k0.y + q0.z * k0.z + q0.w * k0.w
                + q1.x * k1.x + q1.y * k1.y + q1.z * k1.z + q1.w * k1.w;
        // reduce across the 8 lanes of this group
        p += __shfl_xor(p, 1, 64);
        p += __shfl_xor(p, 2, 64);
        p += __shfl_xor(p, 4, 64);
        float l = p * 0.125f;                  // * rsqrt(64)
        float mn = fmaxf(m, l);
        float corr = __expf(m - mn);           // first edge: exp(-inf)=0
        float w = __expf(l - mn);
        float4 v0 = *(const float4*)&v[s * D + j0];
        float4 v1 = *(const float4*)&v[s * D + j0 + 4];
        z = z * corr + w;
        a0.x = fmaf(w, v0.x, a0.x * corr); a0.y = fmaf(w, v0.y, a0.y * corr);
        a0.z = fmaf(w, v0.z, a0.z * corr); a0.w = fmaf(w, v0.w, a0.w * corr);
        a1.x = fmaf(w, v1.x, a1.x * corr); a1.y = fmaf(w, v1.y, a1.y * corr);
        a1.z = fmaf(w, v1.z, a1.z * corr); a1.w = fmaf(w, v1.w, a1.w * corr);
        m = mn;
    }

    if (deg > 0) {
        // merge 8 group softmax states
        float M = m;
        M = fmaxf(M, __shfl_xor(M, 8, 64));
        M = fmaxf(M, __shfl_xor(M, 16, 64));
        M = fmaxf(M, __shfl_xor(M, 32, 64));
        float sc = __expf(m - M);              // empty group: exp(-inf)=0
        float zs = z * sc;
        a0.x *= sc; a0.y *= sc; a0.z *= sc; a0.w *= sc;
        a1.x *= sc; a1.y *= sc; a1.z *= sc; a1.w *= sc;
        #pragma unroll
        for (int off = 8; off < 64; off <<= 1) {
            zs += __shfl_xor(zs, off, 64);
            a0.x += __shfl_xor(a0.x, off, 64); a0.y += __shfl_xor(a0.y, off, 64);
            a0.z += __shfl_xor(a0.z, off, 64); a0.w += __shfl_xor(a0.w, off, 64);
            a1.x += __shfl_xor(a1.x, off, 64); a1.y += __shfl_xor(a1.y, off, 64);
            a1.z += __shfl_xor(a1.z, off, 64); a1.w += __shfl_xor(a1.w, off, 64);
        }
        if (grp == 0) {
            float inv = 1.0f / zs;
            float4 s0 = *(const float4*)&skip[node * D + j0];
            float4 s1 = *(const float4*)&skip[node * D + j0 + 4];
            float4 o0, o1;
            o0.x = fmaf(a0.x, inv, s0.x); o0.y = fmaf(a0.y, inv, s0.y);
            o0.z = fmaf(a0.z, inv, s0.z); o0.w = fmaf(a0.w, inv, s0.w);
            o1.x = fmaf(a1.x, inv, s1.x); o1.y = fmaf(a1.y, inv, s1.y);
            o1.z = fmaf(a1.z, inv, s1.z); o1.w = fmaf(a1.w, inv, s1.w);
            *(float4*)&out[node * D + j0] = o0;
            *(float4*)&out[node * D + j0 + 4] = o1;
        }
    } else if (grp == 0) {
        float4 s0 = *(const float4*)&skip[node * D + j0];
        float4 s1 = *(const float4*)&skip[node * D + j0 + 4];
        *(float4*)&out[node * D + j0] = s0;
        *(float4*)&out[node * D + j0 + 4] = s1;
    }
}

// =============================== launch ====================================

extern "C" void kernel_launch(void* const* d_in, const int* in_sizes, int n_in,
                              void* d_out, int out_size, void* d_ws, size_t ws_size,
                              hipStream_t stream) {
    const float* x  = (const float*)d_in[0];
    const int*   ei = (const int*)d_in[1];
    const float* W1 = (const float*)d_in[2];
    const float* b1 = (const float*)d_in[3];
    const float* Wq = (const float*)d_in[4];
    const float* bq = (const float*)d_in[5];
    const float* Wk = (const float*)d_in[6];
    const float* bk = (const float*)d_in[7];
    const float* Wv = (const float*)d_in[8];
    const float* bv = (const float*)d_in[9];
    const float* Ws = (const float*)d_in[10];
    const float* bs = (const float*)d_in[11];
    const float* W2 = (const float*)d_in[12];
    const float* b2 = (const float*)d_in[13];
    float* out = (float*)d_out;

    const int n = in_sizes[0] / D;   // 50000
    const int e = in_sizes[1] / 2;   // 800000
    const int* src = ei;
    const int* dst = ei + e;
    const int n64 = n * D;

    int* cnt      = (int*)d_ws;
    int* rowptr   = cnt + n;
    int* cursor   = rowptr + n;
    int* partials = cursor + n;
    int* esrc     = partials + 256;
    float* dinv   = (float*)(esrc + e);
    float* bufA   = dinv + n;
    float* bufB   = bufA + (size_t)n64;
    float* bufC   = bufB + (size_t)n64;
    float* bufD   = bufC + (size_t)n64;

    const int nb_n   = (n + 255) / 256;      // 196
    const int nb_e   = (e + 255) / 256;
    const int nb_nw  = (n + 3) / 4;          // wave-per-node, 4 nodes/block
    const int nb_g   = (n + 63) / 64;        // gemm: 64 rows/block

    // ---- CSR build ----
    zero_int_kernel<<<nb_n, 256, 0, stream>>>(cnt, n);
    hist_kernel<<<nb_e, 256, 0, stream>>>(dst, cnt, e);
    scan1_kernel<<<nb_n, 256, 0, stream>>>(cnt, rowptr, partials, dinv, n);
    scan2_kernel<<<1, 256, 0, stream>>>(partials, nb_n);
    scan3_kernel<<<nb_n, 256, 0, stream>>>(rowptr, partials, cursor, n);
    csr_scatter_kernel<<<nb_e, 256, 0, stream>>>(src, dst, cursor, esrc, e);

    // ---- GCN layer 1: x1 = relu(GCN(x) + b1) ----
    gemm64_fast<<<nb_g, 256, 0, stream>>>(x, W1, nullptr, bufA, n);                 // xw1 -> A
    gcn_gather_kernel<<<nb_nw, 256, 0, stream>>>(bufA, dinv, rowptr, cnt, esrc,
                                                 b1, bufB, n, 1);                   // x1 -> B

    // ---- TransformerConv ----
    gemm_qkvs<<<nb_g, 256, 0, stream>>>(bufB, Wq, bq, Wk, bk, Wv, bv, Ws, bs,
                                        bufA, bufC, bufD, out, n);                  // q,k,v,skip
    attn_gather_kernel<<<nb_nw, 256, 0, stream>>>(bufA, bufC, bufD, out,
                                                  rowptr, cnt, esrc, bufB, n);      // x2 -> B

    // ---- GCN layer 2 -> out ----
    gemm64_fast<<<nb_g, 256, 0, stream>>>(bufB, W2, nullptr, bufC, n);              // xw2 -> C
    gcn_gather_kernel<<<nb_nw, 256, 0, stream>>>(bufC, dinv, rowptr, cnt, esrc,
                                                 b2, out, n, 0);
}

// Round 5
// 325.319 us; speedup vs baseline: 3.1229x; 1.1184x over previous
//
#include <hip/hip_runtime.h>
#include <math.h>

// ---------------------------------------------------------------------------
// GraphTransformer: GCNConv(64->64)+ReLU -> TransformerConv(h=1) -> GCNConv(64->64)
// N=50000, E=800000, D=64, fp32 in/out.
// Round 5: edge-gather traffic halved — k/v stored interleaved bf16 (256 B/row),
// GCN xw rows stored bf16 pre-scaled by dinv (128 B/row, kills per-edge dinv
// load). All accumulation fp32. Gathers: 8 groups x 8 lanes per wave.
// ---------------------------------------------------------------------------

#define D 64

// ---- bf16 helpers (RNE) ----------------------------------------------------
__device__ __forceinline__ unsigned short f2bf(float f) {
    unsigned int u = __float_as_uint(f);
    u += 0x7FFFu + ((u >> 16) & 1u);
    return (unsigned short)(u >> 16);
}
// unpack uint (2 bf16) -> 2 floats: low = shift, high = mask
#define BF_LO(u) __uint_as_float((u) << 16)
#define BF_HI(u) __uint_as_float((u) & 0xFFFF0000u)

// ============================ CSR construction =============================

__global__ void zero_int_kernel(int* __restrict__ p, int n) {
    int i = blockIdx.x * blockDim.x + threadIdx.x;
    if (i < n) p[i] = 0;
}

__global__ void hist_kernel(const int* __restrict__ dst, int* __restrict__ cnt, int e) {
    int i = blockIdx.x * blockDim.x + threadIdx.x;
    if (i < e) atomicAdd(&cnt[dst[i]], 1);
}

// scan1 also emits dinv[i] = rsqrt(cnt[i]+1) (self-loop)
__global__ __launch_bounds__(256) void scan1_kernel(const int* __restrict__ cnt,
                                                    int* __restrict__ rowptr,
                                                    int* __restrict__ partials,
                                                    float* __restrict__ dinv, int n) {
    __shared__ int sd[256];
    int t = threadIdx.x, g = blockIdx.x * 256 + t;
    int v = (g < n) ? cnt[g] : 0;
    if (g < n) dinv[g] = rsqrtf((float)v + 1.0f);
    sd[t] = v;
    __syncthreads();
    for (int off = 1; off < 256; off <<= 1) {
        int add = (t >= off) ? sd[t - off] : 0;
        __syncthreads();
        sd[t] += add;
        __syncthreads();
    }
    if (g < n) rowptr[g] = sd[t] - v;       // exclusive
    if (t == 255) partials[blockIdx.x] = sd[t];
}

__global__ __launch_bounds__(256) void scan2_kernel(int* __restrict__ partials, int nb) {
    __shared__ int sd[256];
    int t = threadIdx.x;
    int v = (t < nb) ? partials[t] : 0;
    sd[t] = v;
    __syncthreads();
    for (int off = 1; off < 256; off <<= 1) {
        int add = (t >= off) ? sd[t - off] : 0;
        __syncthreads();
        sd[t] += add;
        __syncthreads();
    }
    if (t < nb) partials[t] = sd[t] - v;    // exclusive
}

__global__ void scan3_kernel(int* __restrict__ rowptr, const int* __restrict__ partials,
                             int* __restrict__ cursor, int n) {
    int g = blockIdx.x * 256 + threadIdx.x;
    if (g < n) {
        int r = rowptr[g] + partials[blockIdx.x];
        rowptr[g] = r;
        cursor[g] = r;
    }
}

__global__ void csr_scatter_kernel(const int* __restrict__ src, const int* __restrict__ dst,
                                   int* __restrict__ cursor, int* __restrict__ esrc, int e) {
    int i = blockIdx.x * blockDim.x + threadIdx.x;
    if (i < e) {
        int pos = atomicAdd(&cursor[dst[i]], 1);
        esrc[pos] = src[i];
    }
}

// ============ GEMM 64x64, epilogue: bf16 output pre-scaled by dinv =========
// xs[row][c] = bf16( (X@W)[row][c] * dinv[row] )
__global__ __launch_bounds__(256) void gemm64_bf16s(const float* __restrict__ X,
                                                    const float* __restrict__ W,
                                                    const float* __restrict__ dinv,
                                                    unsigned short* __restrict__ xs, int n) {
    __shared__ float sX[64][65];
    __shared__ float sW[64 * 64];
    int t = threadIdx.x;
    int base = blockIdx.x * 64;
    #pragma unroll
    for (int i = 0; i < 16; ++i) sW[t + 256 * i] = W[t + 256 * i];
    #pragma unroll
    for (int i = 0; i < 16; ++i) {
        int idx = t + 256 * i;
        int r = idx >> 6, c = idx & 63;
        int row = base + r;
        sX[r][c] = (row < n) ? X[row * D + c] : 0.0f;
    }
    __syncthreads();

    int cg = t & 15, rg = t >> 4;
    int j0 = cg * 4, r0 = rg * 4;
    float acc[4][4];
    #pragma unroll
    for (int a = 0; a < 4; ++a)
        #pragma unroll
        for (int b = 0; b < 4; ++b) acc[a][b] = 0.0f;

    #pragma unroll 8
    for (int k = 0; k < 64; ++k) {
        float4 w = *(const float4*)&sW[k * 64 + j0];
        float x0 = sX[r0 + 0][k];
        float x1 = sX[r0 + 1][k];
        float x2 = sX[r0 + 2][k];
        float x3 = sX[r0 + 3][k];
        acc[0][0] = fmaf(x0, w.x, acc[0][0]); acc[0][1] = fmaf(x0, w.y, acc[0][1]);
        acc[0][2] = fmaf(x0, w.z, acc[0][2]); acc[0][3] = fmaf(x0, w.w, acc[0][3]);
        acc[1][0] = fmaf(x1, w.x, acc[1][0]); acc[1][1] = fmaf(x1, w.y, acc[1][1]);
        acc[1][2] = fmaf(x1, w.z, acc[1][2]); acc[1][3] = fmaf(x1, w.w, acc[1][3]);
        acc[2][0] = fmaf(x2, w.x, acc[2][0]); acc[2][1] = fmaf(x2, w.y, acc[2][1]);
        acc[2][2] = fmaf(x2, w.z, acc[2][2]); acc[2][3] = fmaf(x2, w.w, acc[2][3]);
        acc[3][0] = fmaf(x3, w.x, acc[3][0]); acc[3][1] = fmaf(x3, w.y, acc[3][1]);
        acc[3][2] = fmaf(x3, w.z, acc[3][2]); acc[3][3] = fmaf(x3, w.w, acc[3][3]);
    }

    #pragma unroll
    for (int a = 0; a < 4; ++a) {
        int row = base + r0 + a;
        if (row < n) {
            float dv = dinv[row];
            ushort4 h;
            h.x = f2bf(acc[a][0] * dv);
            h.y = f2bf(acc[a][1] * dv);
            h.z = f2bf(acc[a][2] * dv);
            h.w = f2bf(acc[a][3] * dv);
            *(ushort4*)&xs[(size_t)row * D + j0] = h;
        }
    }
}

// ====== fused QKVS GEMM: q fp32, skip fp32, k/v interleaved bf16 ===========
// kv[row] = [ k[0..63] bf16 | v[0..63] bf16 ]  (256 B per row)
__global__ __launch_bounds__(256) void gemm_qkvs(const float* __restrict__ X,
                                                 const float* __restrict__ Wq,
                                                 const float* __restrict__ bq,
                                                 const float* __restrict__ Wk,
                                                 const float* __restrict__ bk,
                                                 const float* __restrict__ Wv,
                                                 const float* __restrict__ bv,
                                                 const float* __restrict__ Ws,
                                                 const float* __restrict__ bs,
                                                 float* __restrict__ Yq,
                                                 unsigned short* __restrict__ kv,
                                                 float* __restrict__ Ysk, int n) {
    __shared__ float sX[64][65];
    __shared__ float sW[64 * 64];
    int t = threadIdx.x;
    int base = blockIdx.x * 64;
    #pragma unroll
    for (int i = 0; i < 16; ++i) {
        int idx = t + 256 * i;
        int r = idx >> 6, c = idx & 63;
        int row = base + r;
        sX[r][c] = (row < n) ? X[row * D + c] : 0.0f;
    }

    int cg = t & 15, rg = t >> 4;
    int j0 = cg * 4, r0 = rg * 4;

    #pragma unroll 1
    for (int w4 = 0; w4 < 4; ++w4) {
        const float* W = (w4 == 0) ? Wq : (w4 == 1) ? Wk : (w4 == 2) ? Wv : Ws;
        const float* B = (w4 == 0) ? bq : (w4 == 1) ? bk : (w4 == 2) ? bv : bs;
        __syncthreads();   // protect sW from previous iteration's readers
        #pragma unroll
        for (int i = 0; i < 16; ++i) sW[t + 256 * i] = W[t + 256 * i];
        __syncthreads();

        float acc[4][4];
        #pragma unroll
        for (int a = 0; a < 4; ++a)
            #pragma unroll
            for (int b = 0; b < 4; ++b) acc[a][b] = 0.0f;

        #pragma unroll 8
        for (int k = 0; k < 64; ++k) {
            float4 w = *(const float4*)&sW[k * 64 + j0];
            float x0 = sX[r0 + 0][k];
            float x1 = sX[r0 + 1][k];
            float x2 = sX[r0 + 2][k];
            float x3 = sX[r0 + 3][k];
            acc[0][0] = fmaf(x0, w.x, acc[0][0]); acc[0][1] = fmaf(x0, w.y, acc[0][1]);
            acc[0][2] = fmaf(x0, w.z, acc[0][2]); acc[0][3] = fmaf(x0, w.w, acc[0][3]);
            acc[1][0] = fmaf(x1, w.x, acc[1][0]); acc[1][1] = fmaf(x1, w.y, acc[1][1]);
            acc[1][2] = fmaf(x1, w.z, acc[1][2]); acc[1][3] = fmaf(x1, w.w, acc[1][3]);
            acc[2][0] = fmaf(x2, w.x, acc[2][0]); acc[2][1] = fmaf(x2, w.y, acc[2][1]);
            acc[2][2] = fmaf(x2, w.z, acc[2][2]); acc[2][3] = fmaf(x2, w.w, acc[2][3]);
            acc[3][0] = fmaf(x3, w.x, acc[3][0]); acc[3][1] = fmaf(x3, w.y, acc[3][1]);
            acc[3][2] = fmaf(x3, w.z, acc[3][2]); acc[3][3] = fmaf(x3, w.w, acc[3][3]);
        }

        float4 bb = *(const float4*)&B[j0];
        if (w4 == 0 || w4 == 3) {
            float* Y = (w4 == 0) ? Yq : Ysk;
            #pragma unroll
            for (int a = 0; a < 4; ++a) {
                int row = base + r0 + a;
                if (row < n) {
                    float4 o = make_float4(acc[a][0] + bb.x, acc[a][1] + bb.y,
                                           acc[a][2] + bb.z, acc[a][3] + bb.w);
                    *(float4*)&Y[(size_t)row * D + j0] = o;
                }
            }
        } else {
            int off = (w4 == 1) ? 0 : 64;
            #pragma unroll
            for (int a = 0; a < 4; ++a) {
                int row = base + r0 + a;
                if (row < n) {
                    ushort4 h;
                    h.x = f2bf(acc[a][0] + bb.x);
                    h.y = f2bf(acc[a][1] + bb.y);
                    h.z = f2bf(acc[a][2] + bb.z);
                    h.w = f2bf(acc[a][3] + bb.w);
                    *(ushort4*)&kv[(size_t)row * 128 + off + j0] = h;
                }
            }
        }
    }
}

// ===================== GCN gather (bf16 rows, 8x8 grouped) =================
// out[d] = act( dinv[d] * ( xs[d] + sum_{s in in(d)} xs[s] ) + bias )
// where xs = (X@W)*dinv (bf16). wave = node; 8 groups x 8 lanes; lane = 8 feat.
__global__ __launch_bounds__(256) void gcn_gather_kernel(const unsigned short* __restrict__ xs,
                                                         const float* __restrict__ dinv,
                                                         const int* __restrict__ rowptr,
                                                         const int* __restrict__ cnt,
                                                         const int* __restrict__ esrc,
                                                         const float* __restrict__ bias,
                                                         float* __restrict__ out,
                                                         int n, int relu) {
    int node = (blockIdx.x * blockDim.x + threadIdx.x) >> 6;
    if (node >= n) return;
    int lane = threadIdx.x & 63;
    int grp = lane >> 3;          // 0..7
    int sub = lane & 7;           // features sub*8 .. sub*8+7
    int j0 = sub * 8;

    int start = rowptr[node], deg = cnt[node];

    float a[8] = {0.f, 0.f, 0.f, 0.f, 0.f, 0.f, 0.f, 0.f};
    int i = grp;
    int sNext = (i < deg) ? esrc[start + i] : 0;
    for (; i < deg; i += 8) {
        int s = sNext;
        int in = i + 8;
        if (in < deg) sNext = esrc[start + in];
        uint4 r = *(const uint4*)&xs[(size_t)s * D + j0];
        a[0] += BF_LO(r.x); a[1] += BF_HI(r.x);
        a[2] += BF_LO(r.y); a[3] += BF_HI(r.y);
        a[4] += BF_LO(r.z); a[5] += BF_HI(r.z);
        a[6] += BF_LO(r.w); a[7] += BF_HI(r.w);
    }
    // merge 8 group partials: butterfly over lanes ^8, ^16, ^32
    #pragma unroll
    for (int off = 8; off < 64; off <<= 1) {
        #pragma unroll
        for (int c = 0; c < 8; ++c) a[c] += __shfl_xor(a[c], off, 64);
    }

    if (grp == 0) {
        float dd = dinv[node];
        uint4 sr = *(const uint4*)&xs[(size_t)node * D + j0];  // self term
        a[0] += BF_LO(sr.x); a[1] += BF_HI(sr.x);
        a[2] += BF_LO(sr.y); a[3] += BF_HI(sr.y);
        a[4] += BF_LO(sr.z); a[5] += BF_HI(sr.z);
        a[6] += BF_LO(sr.w); a[7] += BF_HI(sr.w);
        float4 b0 = *(const float4*)&bias[j0];
        float4 b1 = *(const float4*)&bias[j0 + 4];
        float o[8];
        o[0] = fmaf(dd, a[0], b0.x); o[1] = fmaf(dd, a[1], b0.y);
        o[2] = fmaf(dd, a[2], b0.z); o[3] = fmaf(dd, a[3], b0.w);
        o[4] = fmaf(dd, a[4], b1.x); o[5] = fmaf(dd, a[5], b1.y);
        o[6] = fmaf(dd, a[6], b1.z); o[7] = fmaf(dd, a[7], b1.w);
        if (relu) {
            #pragma unroll
            for (int c = 0; c < 8; ++c) o[c] = fmaxf(o[c], 0.f);
        }
        float4 w0 = make_float4(o[0], o[1], o[2], o[3]);
        float4 w1 = make_float4(o[4], o[5], o[6], o[7]);
        *(float4*)&out[(size_t)node * D + j0] = w0;
        *(float4*)&out[(size_t)node * D + j0 + 4] = w1;
    }
}

// ======= fused attention gather (bf16 interleaved kv, 8x8 online softmax) ==
__global__ __launch_bounds__(256) void attn_gather_kernel(const float* __restrict__ q,
                                                          const unsigned short* __restrict__ kv,
                                                          const float* __restrict__ skip,
                                                          const int* __restrict__ rowptr,
                                                          const int* __restrict__ cnt,
                                                          const int* __restrict__ esrc,
                                                          float* __restrict__ out, int n) {
    int node = (blockIdx.x * blockDim.x + threadIdx.x) >> 6;
    if (node >= n) return;
    int lane = threadIdx.x & 63;
    int grp = lane >> 3;
    int sub = lane & 7;
    int j0 = sub * 8;

    int start = rowptr[node], deg = cnt[node];
    float4 q0 = *(const float4*)&q[(size_t)node * D + j0];
    float4 q1 = *(const float4*)&q[(size_t)node * D + j0 + 4];

    float m = -INFINITY, z = 0.0f;
    float a[8] = {0.f, 0.f, 0.f, 0.f, 0.f, 0.f, 0.f, 0.f};

    int i = grp;
    int sNext = (i < deg) ? esrc[start + i] : 0;
    for (; i < deg; i += 8) {
        int s = sNext;
        int in = i + 8;
        if (in < deg) sNext = esrc[start + in];
        const unsigned short* row = kv + (size_t)s * 128;
        uint4 kr = *(const uint4*)&row[j0];         // k half
        uint4 vr = *(const uint4*)&row[64 + j0];    // v half
        float p = q0.x * BF_LO(kr.x) + q0.y * BF_HI(kr.x)
                + q0.z * BF_LO(kr.y) + q0.w * BF_HI(kr.y)
                + q1.x * BF_LO(kr.z) + q1.y * BF_HI(kr.z)
                + q1.z * BF_LO(kr.w) + q1.w * BF_HI(kr.w);
        // reduce across the 8 lanes of this group
        p += __shfl_xor(p, 1, 64);
        p += __shfl_xor(p, 2, 64);
        p += __shfl_xor(p, 4, 64);
        float l = p * 0.125f;                  // * rsqrt(64)
        float mn = fmaxf(m, l);
        float corr = __expf(m - mn);           // first edge: exp(-inf)=0
        float w = __expf(l - mn);
        z = z * corr + w;
        a[0] = fmaf(w, BF_LO(vr.x), a[0] * corr);
        a[1] = fmaf(w, BF_HI(vr.x), a[1] * corr);
        a[2] = fmaf(w, BF_LO(vr.y), a[2] * corr);
        a[3] = fmaf(w, BF_HI(vr.y), a[3] * corr);
        a[4] = fmaf(w, BF_LO(vr.z), a[4] * corr);
        a[5] = fmaf(w, BF_HI(vr.z), a[5] * corr);
        a[6] = fmaf(w, BF_LO(vr.w), a[6] * corr);
        a[7] = fmaf(w, BF_HI(vr.w), a[7] * corr);
        m = mn;
    }

    float4 s0 = (grp == 0) ? *(const float4*)&skip[(size_t)node * D + j0]
                           : make_float4(0.f, 0.f, 0.f, 0.f);
    float4 s1 = (grp == 0) ? *(const float4*)&skip[(size_t)node * D + j0 + 4]
                           : make_float4(0.f, 0.f, 0.f, 0.f);

    if (deg > 0) {
        // merge 8 group softmax states
        float M = m;
        M = fmaxf(M, __shfl_xor(M, 8, 64));
        M = fmaxf(M, __shfl_xor(M, 16, 64));
        M = fmaxf(M, __shfl_xor(M, 32, 64));
        float sc = __expf(m - M);              // empty group: exp(-inf)=0
        float zs = z * sc;
        #pragma unroll
        for (int c = 0; c < 8; ++c) a[c] *= sc;
        #pragma unroll
        for (int off = 8; off < 64; off <<= 1) {
            zs += __shfl_xor(zs, off, 64);
            #pragma unroll
            for (int c = 0; c < 8; ++c) a[c] += __shfl_xor(a[c], off, 64);
        }
        if (grp == 0) {
            float inv = 1.0f / zs;
            float4 o0, o1;
            o0.x = fmaf(a[0], inv, s0.x); o0.y = fmaf(a[1], inv, s0.y);
            o0.z = fmaf(a[2], inv, s0.z); o0.w = fmaf(a[3], inv, s0.w);
            o1.x = fmaf(a[4], inv, s1.x); o1.y = fmaf(a[5], inv, s1.y);
            o1.z = fmaf(a[6], inv, s1.z); o1.w = fmaf(a[7], inv, s1.w);
            *(float4*)&out[(size_t)node * D + j0] = o0;
            *(float4*)&out[(size_t)node * D + j0 + 4] = o1;
        }
    } else if (grp == 0) {
        *(float4*)&out[(size_t)node * D + j0] = s0;
        *(float4*)&out[(size_t)node * D + j0 + 4] = s1;
    }
}

// =============================== launch ====================================

extern "C" void kernel_launch(void* const* d_in, const int* in_sizes, int n_in,
                              void* d_out, int out_size, void* d_ws, size_t ws_size,
                              hipStream_t stream) {
    const float* x  = (const float*)d_in[0];
    const int*   ei = (const int*)d_in[1];
    const float* W1 = (const float*)d_in[2];
    const float* b1 = (const float*)d_in[3];
    const float* Wq = (const float*)d_in[4];
    const float* bq = (const float*)d_in[5];
    const float* Wk = (const float*)d_in[6];
    const float* bk = (const float*)d_in[7];
    const float* Wv = (const float*)d_in[8];
    const float* bv = (const float*)d_in[9];
    const float* Ws = (const float*)d_in[10];
    const float* bs = (const float*)d_in[11];
    const float* W2 = (const float*)d_in[12];
    const float* b2 = (const float*)d_in[13];
    float* out = (float*)d_out;

    const int n = in_sizes[0] / D;   // 50000
    const int e = in_sizes[1] / 2;   // 800000
    const int* src = ei;
    const int* dst = ei + e;
    const int n64 = n * D;

    // ---- workspace layout ----
    int* cnt      = (int*)d_ws;
    int* rowptr   = cnt + n;
    int* cursor   = rowptr + n;
    int* partials = cursor + n;
    int* esrc     = partials + 256;
    float* dinv   = (float*)(esrc + e);
    float* bufA   = dinv + n;                      // q
    float* bufB   = bufA + (size_t)n64;            // x1, then x2
    unsigned short* xs = (unsigned short*)(bufB + (size_t)n64);  // n*64 bf16 (xw*dinv)
    unsigned short* kv = xs + (size_t)n64;         // n*128 bf16 (k|v interleaved)

    const int nb_n   = (n + 255) / 256;      // 196
    const int nb_e   = (e + 255) / 256;
    const int nb_nw  = (n + 3) / 4;          // wave-per-node, 4 nodes/block
    const int nb_g   = (n + 63) / 64;        // gemm: 64 rows/block

    // ---- CSR build ----
    zero_int_kernel<<<nb_n, 256, 0, stream>>>(cnt, n);
    hist_kernel<<<nb_e, 256, 0, stream>>>(dst, cnt, e);
    scan1_kernel<<<nb_n, 256, 0, stream>>>(cnt, rowptr, partials, dinv, n);
    scan2_kernel<<<1, 256, 0, stream>>>(partials, nb_n);
    scan3_kernel<<<nb_n, 256, 0, stream>>>(rowptr, partials, cursor, n);
    csr_scatter_kernel<<<nb_e, 256, 0, stream>>>(src, dst, cursor, esrc, e);

    // ---- GCN layer 1: x1 = relu(dinv*(sum xs) + b1), xs = (x@W1)*dinv ----
    gemm64_bf16s<<<nb_g, 256, 0, stream>>>(x, W1, dinv, xs, n);
    gcn_gather_kernel<<<nb_nw, 256, 0, stream>>>(xs, dinv, rowptr, cnt, esrc,
                                                 b1, bufB, n, 1);                   // x1 -> B

    // ---- TransformerConv ----
    gemm_qkvs<<<nb_g, 256, 0, stream>>>(bufB, Wq, bq, Wk, bk, Wv, bv, Ws, bs,
                                        bufA, kv, out, n);                          // q, kv, skip
    attn_gather_kernel<<<nb_nw, 256, 0, stream>>>(bufA, kv, out,
                                                  rowptr, cnt, esrc, bufB, n);      // x2 -> B

    // ---- GCN layer 2 -> out ----
    gemm64_bf16s<<<nb_g, 256, 0, stream>>>(bufB, W2, dinv, xs, n);
    gcn_gather_kernel<<<nb_nw, 256, 0, stream>>>(xs, dinv, rowptr, cnt, esrc,
                                                 b2, out, n, 0);
}

// Round 6
// 254.877 us; speedup vs baseline: 3.9860x; 1.2764x over previous
//
#include <hip/hip_runtime.h>
#include <math.h>

// ---------------------------------------------------------------------------
// GraphTransformer: GCNConv(64->64)+ReLU -> TransformerConv(h=1) -> GCNConv(64->64)
// N=50000, E=800000, D=64, fp32 in/out.
// Round 6:
//  * CSR build rewritten as 2-phase LDS binning (no 64B-per-4B write amp):
//    binA: chunk-local counting sort by coarse bucket (512 nodes), coalesced
//          run writes of packed (dst<<16|src).  [requires n < 65536]
//    binB: per-bucket LDS counting sort -> cnt/rowptr/dinv/esrc(uint16).
//  * GEMMs: k-unroll x4, all-float4 LDS traffic (VALU-bound now).
//  * attention scale 1/8 folded into q epilogue.
// ---------------------------------------------------------------------------

#define D 64
#define BKT_SHIFT 9              // 512 nodes per bucket
#define CAP 12288                // staging capacity per bucket (avg ~8163)
#define CHUNK 4096               // edges per workgroup in binA

// ---- bf16 helpers (RNE) ----------------------------------------------------
__device__ __forceinline__ unsigned short f2bf(float f) {
    unsigned int u = __float_as_uint(f);
    u += 0x7FFFu + ((u >> 16) & 1u);
    return (unsigned short)(u >> 16);
}
#define BF_LO(u) __uint_as_float((u) << 16)
#define BF_HI(u) __uint_as_float((u) & 0xFFFF0000u)

// ============================ CSR build ====================================

__global__ void init_gcursor(int* __restrict__ gcursor) {
    if (threadIdx.x < 128) gcursor[threadIdx.x] = 0;
}

// binA: bin edges into coarse buckets with coalesced run writes.
__global__ __launch_bounds__(256) void binA_kernel(const int* __restrict__ src,
                                                   const int* __restrict__ dst,
                                                   int* __restrict__ gcursor,
                                                   unsigned int* __restrict__ staging,
                                                   int e, int nbkt) {
    __shared__ int cntB[128];
    __shared__ int offB[128];
    __shared__ int curB[128];
    __shared__ int gbase[128];
    __shared__ unsigned int pairs[CHUNK];
    __shared__ unsigned char bkt[CHUNK];

    int t = threadIdx.x;
    int e0 = blockIdx.x * CHUNK;
    int ecnt = min(CHUNK, e - e0);

    if (t < 128) cntB[t] = 0;
    __syncthreads();

    int myS[CHUNK / 256], myD[CHUNK / 256];
    #pragma unroll
    for (int i = 0; i < CHUNK / 256; ++i) {
        int idx = t + 256 * i;
        if (idx < ecnt) {
            myS[i] = src[e0 + idx];
            myD[i] = dst[e0 + idx];
            atomicAdd(&cntB[myD[i] >> BKT_SHIFT], 1);
        }
    }
    __syncthreads();
    // scan 128 (inclusive Hillis-Steele)
    if (t < 128) offB[t] = cntB[t];
    __syncthreads();
    for (int off = 1; off < 128; off <<= 1) {
        int add = (t < 128 && t >= off) ? offB[t - off] : 0;
        __syncthreads();
        if (t < 128) offB[t] += add;
        __syncthreads();
    }
    if (t < 128) {
        int excl = offB[t] - cntB[t];
        offB[t] = excl;
        curB[t] = excl;
        if (t < nbkt && cntB[t] > 0) gbase[t] = atomicAdd(&gcursor[t], cntB[t]);
    }
    __syncthreads();
    // place into bucket-sorted LDS array
    #pragma unroll
    for (int i = 0; i < CHUNK / 256; ++i) {
        int idx = t + 256 * i;
        if (idx < ecnt) {
            int b = myD[i] >> BKT_SHIFT;
            int p = atomicAdd(&curB[b], 1);
            pairs[p] = ((unsigned int)myD[i] << 16) | (unsigned int)myS[i];
            bkt[p] = (unsigned char)b;
        }
    }
    __syncthreads();
    // copy out: contiguous run per bucket
    for (int p = t; p < ecnt; p += 256) {
        int b = bkt[p];
        staging[(size_t)b * CAP + gbase[b] + (p - offB[b])] = pairs[p];
    }
}

// binB: one workgroup per bucket -> cnt/rowptr/dinv + dst-sorted esrc (uint16)
__global__ __launch_bounds__(256) void binB_kernel(const int* __restrict__ gcursor,
                                                   const unsigned int* __restrict__ staging,
                                                   unsigned short* __restrict__ esrc,
                                                   int* __restrict__ cnt,
                                                   int* __restrict__ rowptr,
                                                   float* __restrict__ dinv,
                                                   int n, int nbkt) {
    __shared__ int bpre[128];
    __shared__ int c512[512];
    __shared__ int o512[512];
    int t = threadIdx.x;
    int b = blockIdx.x;

    // prefix over bucket sizes -> esrc base of this bucket
    if (t < 128) bpre[t] = (t < nbkt) ? gcursor[t] : 0;
    __syncthreads();
    for (int off = 1; off < 128; off <<= 1) {
        int add = (t < 128 && t >= off) ? bpre[t - off] : 0;
        __syncthreads();
        if (t < 128) bpre[t] += add;
        __syncthreads();
    }
    int base_b = (b == 0) ? 0 : bpre[b - 1];
    int cnt_b = gcursor[b];
    int lo = b << BKT_SHIFT;

    c512[t] = 0; c512[t + 256] = 0;
    __syncthreads();
    const unsigned int* st = staging + (size_t)b * CAP;
    for (int i = t; i < cnt_b; i += 256)
        atomicAdd(&c512[(int)(st[i] >> 16) - lo], 1);
    __syncthreads();
    // scan 512 (inclusive), 2 elems/thread
    o512[t] = c512[t]; o512[t + 256] = c512[t + 256];
    __syncthreads();
    for (int off = 1; off < 512; off <<= 1) {
        int a1 = (t >= off) ? o512[t - off] : 0;
        int a2 = o512[t + 256 - off];
        __syncthreads();
        o512[t] += a1; o512[t + 256] += a2;
        __syncthreads();
    }
    // to exclusive (these become the scatter cursors too)
    int e1 = o512[t] - c512[t];
    int e2 = o512[t + 256] - c512[t + 256];
    __syncthreads();
    o512[t] = e1; o512[t + 256] = e2;
    __syncthreads();
    // node outputs
    for (int i = t; i < 512; i += 256) {
        int g = lo + i;
        if (g < n) {
            int c = c512[i];
            cnt[g] = c;
            rowptr[g] = base_b + o512[i];
            dinv[g] = rsqrtf((float)c + 1.0f);
        }
    }
    __syncthreads();
    // scatter esrc within this bucket's window (L2-absorbed)
    for (int i = t; i < cnt_b; i += 256) {
        unsigned int pk = st[i];
        int local = (int)(pk >> 16) - lo;
        int p = atomicAdd(&o512[local], 1);
        esrc[base_b + p] = (unsigned short)(pk & 0xFFFFu);
    }
}

// ============ GEMM 64x64, epilogue: bf16 output pre-scaled by dinv =========
__global__ __launch_bounds__(256) void gemm64_bf16s(const float* __restrict__ X,
                                                    const float* __restrict__ W,
                                                    const float* __restrict__ dinv,
                                                    unsigned short* __restrict__ xs, int n) {
    __shared__ float sX[64][68];   // 68: 16B-aligned rows, 2-way-max banks
    __shared__ float sW[64 * 64];
    int t = threadIdx.x;
    int base = blockIdx.x * 64;
    #pragma unroll
    for (int i = 0; i < 4; ++i) {
        int f = t * 4 + i * 1024;
        *(float4*)&sW[f] = *(const float4*)&W[f];
        int r = f >> 6, c = f & 63;
        int row = base + r;
        float4 xv = (row < n) ? *(const float4*)&X[(size_t)row * D + c]
                              : make_float4(0.f, 0.f, 0.f, 0.f);
        *(float4*)&sX[r][c] = xv;
    }
    __syncthreads();

    int cg = t & 15, rg = t >> 4;
    int j0 = cg * 4, r0 = rg * 4;
    float acc[4][4];
    #pragma unroll
    for (int a = 0; a < 4; ++a)
        #pragma unroll
        for (int c = 0; c < 4; ++c) acc[a][c] = 0.0f;

    #pragma unroll 4
    for (int kk = 0; kk < 64; kk += 4) {
        float4 w0 = *(const float4*)&sW[(kk + 0) * 64 + j0];
        float4 w1 = *(const float4*)&sW[(kk + 1) * 64 + j0];
        float4 w2 = *(const float4*)&sW[(kk + 2) * 64 + j0];
        float4 w3 = *(const float4*)&sW[(kk + 3) * 64 + j0];
        #pragma unroll
        for (int a = 0; a < 4; ++a) {
            float4 xv = *(const float4*)&sX[r0 + a][kk];
            acc[a][0] = fmaf(xv.x, w0.x, acc[a][0]); acc[a][1] = fmaf(xv.x, w0.y, acc[a][1]);
            acc[a][2] = fmaf(xv.x, w0.z, acc[a][2]); acc[a][3] = fmaf(xv.x, w0.w, acc[a][3]);
            acc[a][0] = fmaf(xv.y, w1.x, acc[a][0]); acc[a][1] = fmaf(xv.y, w1.y, acc[a][1]);
            acc[a][2] = fmaf(xv.y, w1.z, acc[a][2]); acc[a][3] = fmaf(xv.y, w1.w, acc[a][3]);
            acc[a][0] = fmaf(xv.z, w2.x, acc[a][0]); acc[a][1] = fmaf(xv.z, w2.y, acc[a][1]);
            acc[a][2] = fmaf(xv.z, w2.z, acc[a][2]); acc[a][3] = fmaf(xv.z, w2.w, acc[a][3]);
            acc[a][0] = fmaf(xv.w, w3.x, acc[a][0]); acc[a][1] = fmaf(xv.w, w3.y, acc[a][1]);
            acc[a][2] = fmaf(xv.w, w3.z, acc[a][2]); acc[a][3] = fmaf(xv.w, w3.w, acc[a][3]);
        }
    }

    #pragma unroll
    for (int a = 0; a < 4; ++a) {
        int row = base + r0 + a;
        if (row < n) {
            float dv = dinv[row];
            ushort4 h;
            h.x = f2bf(acc[a][0] * dv);
            h.y = f2bf(acc[a][1] * dv);
            h.z = f2bf(acc[a][2] * dv);
            h.w = f2bf(acc[a][3] * dv);
            *(ushort4*)&xs[(size_t)row * D + j0] = h;
        }
    }
}

// ====== fused QKVS GEMM: q fp32 (pre-scaled 1/8), skip fp32, k/v bf16 ======
__global__ __launch_bounds__(256) void gemm_qkvs(const float* __restrict__ X,
                                                 const float* __restrict__ Wq,
                                                 const float* __restrict__ bq,
                                                 const float* __restrict__ Wk,
                                                 const float* __restrict__ bk,
                                                 const float* __restrict__ Wv,
                                                 const float* __restrict__ bv,
                                                 const float* __restrict__ Ws,
                                                 const float* __restrict__ bs,
                                                 float* __restrict__ Yq,
                                                 unsigned short* __restrict__ kv,
                                                 float* __restrict__ Ysk, int n) {
    __shared__ float sX[64][68];
    __shared__ float sW[64 * 64];
    int t = threadIdx.x;
    int base = blockIdx.x * 64;
    #pragma unroll
    for (int i = 0; i < 4; ++i) {
        int f = t * 4 + i * 1024;
        int r = f >> 6, c = f & 63;
        int row = base + r;
        float4 xv = (row < n) ? *(const float4*)&X[(size_t)row * D + c]
                              : make_float4(0.f, 0.f, 0.f, 0.f);
        *(float4*)&sX[r][c] = xv;
    }

    int cg = t & 15, rg = t >> 4;
    int j0 = cg * 4, r0 = rg * 4;

    #pragma unroll 1
    for (int w4 = 0; w4 < 4; ++w4) {
        const float* W = (w4 == 0) ? Wq : (w4 == 1) ? Wk : (w4 == 2) ? Wv : Ws;
        const float* B = (w4 == 0) ? bq : (w4 == 1) ? bk : (w4 == 2) ? bv : bs;
        __syncthreads();   // protect sW from previous iteration's readers
        #pragma unroll
        for (int i = 0; i < 4; ++i) {
            int f = t * 4 + i * 1024;
            *(float4*)&sW[f] = *(const float4*)&W[f];
        }
        __syncthreads();

        float acc[4][4];
        #pragma unroll
        for (int a = 0; a < 4; ++a)
            #pragma unroll
            for (int c = 0; c < 4; ++c) acc[a][c] = 0.0f;

        #pragma unroll 4
        for (int kk = 0; kk < 64; kk += 4) {
            float4 w0 = *(const float4*)&sW[(kk + 0) * 64 + j0];
            float4 w1 = *(const float4*)&sW[(kk + 1) * 64 + j0];
            float4 w2 = *(const float4*)&sW[(kk + 2) * 64 + j0];
            float4 w3 = *(const float4*)&sW[(kk + 3) * 64 + j0];
            #pragma unroll
            for (int a = 0; a < 4; ++a) {
                float4 xv = *(const float4*)&sX[r0 + a][kk];
                acc[a][0] = fmaf(xv.x, w0.x, acc[a][0]); acc[a][1] = fmaf(xv.x, w0.y, acc[a][1]);
                acc[a][2] = fmaf(xv.x, w0.z, acc[a][2]); acc[a][3] = fmaf(xv.x, w0.w, acc[a][3]);
                acc[a][0] = fmaf(xv.y, w1.x, acc[a][0]); acc[a][1] = fmaf(xv.y, w1.y, acc[a][1]);
                acc[a][2] = fmaf(xv.y, w1.z, acc[a][2]); acc[a][3] = fmaf(xv.y, w1.w, acc[a][3]);
                acc[a][0] = fmaf(xv.z, w2.x, acc[a][0]); acc[a][1] = fmaf(xv.z, w2.y, acc[a][1]);
                acc[a][2] = fmaf(xv.z, w2.z, acc[a][2]); acc[a][3] = fmaf(xv.z, w2.w, acc[a][3]);
                acc[a][0] = fmaf(xv.w, w3.x, acc[a][0]); acc[a][1] = fmaf(xv.w, w3.y, acc[a][1]);
                acc[a][2] = fmaf(xv.w, w3.z, acc[a][2]); acc[a][3] = fmaf(xv.w, w3.w, acc[a][3]);
            }
        }

        float4 bb = *(const float4*)&B[j0];
        if (w4 == 0) {
            #pragma unroll
            for (int a = 0; a < 4; ++a) {
                int row = base + r0 + a;
                if (row < n) {
                    float4 o = make_float4((acc[a][0] + bb.x) * 0.125f,
                                           (acc[a][1] + bb.y) * 0.125f,
                                           (acc[a][2] + bb.z) * 0.125f,
                                           (acc[a][3] + bb.w) * 0.125f);
                    *(float4*)&Yq[(size_t)row * D + j0] = o;
                }
            }
        } else if (w4 == 3) {
            #pragma unroll
            for (int a = 0; a < 4; ++a) {
                int row = base + r0 + a;
                if (row < n) {
                    float4 o = make_float4(acc[a][0] + bb.x, acc[a][1] + bb.y,
                                           acc[a][2] + bb.z, acc[a][3] + bb.w);
                    *(float4*)&Ysk[(size_t)row * D + j0] = o;
                }
            }
        } else {
            int off = (w4 == 1) ? 0 : 64;
            #pragma unroll
            for (int a = 0; a < 4; ++a) {
                int row = base + r0 + a;
                if (row < n) {
                    ushort4 h;
                    h.x = f2bf(acc[a][0] + bb.x);
                    h.y = f2bf(acc[a][1] + bb.y);
                    h.z = f2bf(acc[a][2] + bb.z);
                    h.w = f2bf(acc[a][3] + bb.w);
                    *(ushort4*)&kv[(size_t)row * 128 + off + j0] = h;
                }
            }
        }
    }
}

// ===================== GCN gather (bf16 rows, 8x8 grouped) =================
__global__ __launch_bounds__(256) void gcn_gather_kernel(const unsigned short* __restrict__ xs,
                                                         const float* __restrict__ dinv,
                                                         const int* __restrict__ rowptr,
                                                         const int* __restrict__ cnt,
                                                         const unsigned short* __restrict__ esrc,
                                                         const float* __restrict__ bias,
                                                         float* __restrict__ out,
                                                         int n, int relu) {
    int node = (blockIdx.x * blockDim.x + threadIdx.x) >> 6;
    if (node >= n) return;
    int lane = threadIdx.x & 63;
    int grp = lane >> 3;          // 0..7
    int sub = lane & 7;
    int j0 = sub * 8;

    int start = rowptr[node], deg = cnt[node];

    float a[8] = {0.f, 0.f, 0.f, 0.f, 0.f, 0.f, 0.f, 0.f};
    int i = grp;
    int sNext = (i < deg) ? esrc[start + i] : 0;
    for (; i < deg; i += 8) {
        int s = sNext;
        int in = i + 8;
        if (in < deg) sNext = esrc[start + in];
        uint4 r = *(const uint4*)&xs[(size_t)s * D + j0];
        a[0] += BF_LO(r.x); a[1] += BF_HI(r.x);
        a[2] += BF_LO(r.y); a[3] += BF_HI(r.y);
        a[4] += BF_LO(r.z); a[5] += BF_HI(r.z);
        a[6] += BF_LO(r.w); a[7] += BF_HI(r.w);
    }
    #pragma unroll
    for (int off = 8; off < 64; off <<= 1) {
        #pragma unroll
        for (int c = 0; c < 8; ++c) a[c] += __shfl_xor(a[c], off, 64);
    }

    if (grp == 0) {
        float dd = dinv[node];
        uint4 sr = *(const uint4*)&xs[(size_t)node * D + j0];  // self term
        a[0] += BF_LO(sr.x); a[1] += BF_HI(sr.x);
        a[2] += BF_LO(sr.y); a[3] += BF_HI(sr.y);
        a[4] += BF_LO(sr.z); a[5] += BF_HI(sr.z);
        a[6] += BF_LO(sr.w); a[7] += BF_HI(sr.w);
        float4 b0 = *(const float4*)&bias[j0];
        float4 b1 = *(const float4*)&bias[j0 + 4];
        float o[8];
        o[0] = fmaf(dd, a[0], b0.x); o[1] = fmaf(dd, a[1], b0.y);
        o[2] = fmaf(dd, a[2], b0.z); o[3] = fmaf(dd, a[3], b0.w);
        o[4] = fmaf(dd, a[4], b1.x); o[5] = fmaf(dd, a[5], b1.y);
        o[6] = fmaf(dd, a[6], b1.z); o[7] = fmaf(dd, a[7], b1.w);
        if (relu) {
            #pragma unroll
            for (int c = 0; c < 8; ++c) o[c] = fmaxf(o[c], 0.f);
        }
        *(float4*)&out[(size_t)node * D + j0] = make_float4(o[0], o[1], o[2], o[3]);
        *(float4*)&out[(size_t)node * D + j0 + 4] = make_float4(o[4], o[5], o[6], o[7]);
    }
}

// ======= fused attention gather (bf16 interleaved kv, 8x8 online softmax) ==
__global__ __launch_bounds__(256) void attn_gather_kernel(const float* __restrict__ q,
                                                          const unsigned short* __restrict__ kv,
                                                          const float* __restrict__ skip,
                                                          const int* __restrict__ rowptr,
                                                          const int* __restrict__ cnt,
                                                          const unsigned short* __restrict__ esrc,
                                                          float* __restrict__ out, int n) {
    int node = (blockIdx.x * blockDim.x + threadIdx.x) >> 6;
    if (node >= n) return;
    int lane = threadIdx.x & 63;
    int grp = lane >> 3;
    int sub = lane & 7;
    int j0 = sub * 8;

    int start = rowptr[node], deg = cnt[node];
    float4 q0 = *(const float4*)&q[(size_t)node * D + j0];      // pre-scaled by 1/8
    float4 q1 = *(const float4*)&q[(size_t)node * D + j0 + 4];

    float m = -INFINITY, z = 0.0f;
    float a[8] = {0.f, 0.f, 0.f, 0.f, 0.f, 0.f, 0.f, 0.f};

    int i = grp;
    int sNext = (i < deg) ? esrc[start + i] : 0;
    for (; i < deg; i += 8) {
        int s = sNext;
        int in = i + 8;
        if (in < deg) sNext = esrc[start + in];
        const unsigned short* row = kv + (size_t)s * 128;
        uint4 kr = *(const uint4*)&row[j0];
        uint4 vr = *(const uint4*)&row[64 + j0];
        float p = q0.x * BF_LO(kr.x) + q0.y * BF_HI(kr.x)
                + q0.z * BF_LO(kr.y) + q0.w * BF_HI(kr.y)
                + q1.x * BF_LO(kr.z) + q1.y * BF_HI(kr.z)
                + q1.z * BF_LO(kr.w) + q1.w * BF_HI(kr.w);
        p += __shfl_xor(p, 1, 64);
        p += __shfl_xor(p, 2, 64);
        p += __shfl_xor(p, 4, 64);
        float l = p;                           // scale folded into q
        float mn = fmaxf(m, l);
        float corr = __expf(m - mn);
        float w = __expf(l - mn);
        z = z * corr + w;
        a[0] = fmaf(w, BF_LO(vr.x), a[0] * corr);
        a[1] = fmaf(w, BF_HI(vr.x), a[1] * corr);
        a[2] = fmaf(w, BF_LO(vr.y), a[2] * corr);
        a[3] = fmaf(w, BF_HI(vr.y), a[3] * corr);
        a[4] = fmaf(w, BF_LO(vr.z), a[4] * corr);
        a[5] = fmaf(w, BF_HI(vr.z), a[5] * corr);
        a[6] = fmaf(w, BF_LO(vr.w), a[6] * corr);
        a[7] = fmaf(w, BF_HI(vr.w), a[7] * corr);
        m = mn;
    }

    float4 s0 = (grp == 0) ? *(const float4*)&skip[(size_t)node * D + j0]
                           : make_float4(0.f, 0.f, 0.f, 0.f);
    float4 s1 = (grp == 0) ? *(const float4*)&skip[(size_t)node * D + j0 + 4]
                           : make_float4(0.f, 0.f, 0.f, 0.f);

    if (deg > 0) {
        float M = m;
        M = fmaxf(M, __shfl_xor(M, 8, 64));
        M = fmaxf(M, __shfl_xor(M, 16, 64));
        M = fmaxf(M, __shfl_xor(M, 32, 64));
        float sc = __expf(m - M);
        float zs = z * sc;
        #pragma unroll
        for (int c = 0; c < 8; ++c) a[c] *= sc;
        #pragma unroll
        for (int off = 8; off < 64; off <<= 1) {
            zs += __shfl_xor(zs, off, 64);
            #pragma unroll
            for (int c = 0; c < 8; ++c) a[c] += __shfl_xor(a[c], off, 64);
        }
        if (grp == 0) {
            float inv = 1.0f / zs;
            float4 o0, o1;
            o0.x = fmaf(a[0], inv, s0.x); o0.y = fmaf(a[1], inv, s0.y);
            o0.z = fmaf(a[2], inv, s0.z); o0.w = fmaf(a[3], inv, s0.w);
            o1.x = fmaf(a[4], inv, s1.x); o1.y = fmaf(a[5], inv, s1.y);
            o1.z = fmaf(a[6], inv, s1.z); o1.w = fmaf(a[7], inv, s1.w);
            *(float4*)&out[(size_t)node * D + j0] = o0;
            *(float4*)&out[(size_t)node * D + j0 + 4] = o1;
        }
    } else if (grp == 0) {
        *(float4*)&out[(size_t)node * D + j0] = s0;
        *(float4*)&out[(size_t)node * D + j0 + 4] = s1;
    }
}

// =============================== launch ====================================

extern "C" void kernel_launch(void* const* d_in, const int* in_sizes, int n_in,
                              void* d_out, int out_size, void* d_ws, size_t ws_size,
                              hipStream_t stream) {
    const float* x  = (const float*)d_in[0];
    const int*   ei = (const int*)d_in[1];
    const float* W1 = (const float*)d_in[2];
    const float* b1 = (const float*)d_in[3];
    const float* Wq = (const float*)d_in[4];
    const float* bq = (const float*)d_in[5];
    const float* Wk = (const float*)d_in[6];
    const float* bk = (const float*)d_in[7];
    const float* Wv = (const float*)d_in[8];
    const float* bv = (const float*)d_in[9];
    const float* Ws = (const float*)d_in[10];
    const float* bs = (const float*)d_in[11];
    const float* W2 = (const float*)d_in[12];
    const float* b2 = (const float*)d_in[13];
    float* out = (float*)d_out;

    const int n = in_sizes[0] / D;   // 50000  (must be < 65536 for 16-bit packing)
    const int e = in_sizes[1] / 2;   // 800000
    const int* src = ei;
    const int* dst = ei + e;
    const int n64 = n * D;
    const int nbkt = (n + (1 << BKT_SHIFT) - 1) >> BKT_SHIFT;   // 98

    // ---- workspace carve (256B-aligned chunks) ----
    char* w = (char*)d_ws;
    auto carve = [&](size_t bytes) {
        char* p = w;
        w += (bytes + 255) & ~(size_t)255;
        return p;
    };
    int* gcursor            = (int*)carve(128 * 4);
    unsigned int* staging   = (unsigned int*)carve((size_t)nbkt * CAP * 4);
    unsigned short* esrc    = (unsigned short*)carve((size_t)e * 2);
    int* cnt                = (int*)carve((size_t)n * 4);
    int* rowptr             = (int*)carve((size_t)n * 4);
    float* dinv             = (float*)carve((size_t)n * 4);
    float* bufA             = (float*)carve((size_t)n64 * 4);   // q
    float* bufB             = (float*)carve((size_t)n64 * 4);   // x1, then x2
    unsigned short* xs      = (unsigned short*)carve((size_t)n64 * 2);
    unsigned short* kv      = (unsigned short*)carve((size_t)n64 * 4);  // k|v bf16

    const int nb_binA = (e + CHUNK - 1) / CHUNK;   // 196
    const int nb_nw   = (n + 3) / 4;               // wave-per-node
    const int nb_g    = (n + 63) / 64;             // gemm: 64 rows/block

    // ---- CSR build (2-phase binning) ----
    init_gcursor<<<1, 128, 0, stream>>>(gcursor);
    binA_kernel<<<nb_binA, 256, 0, stream>>>(src, dst, gcursor, staging, e, nbkt);
    binB_kernel<<<nbkt, 256, 0, stream>>>(gcursor, staging, esrc, cnt, rowptr, dinv, n, nbkt);

    // ---- GCN layer 1 ----
    gemm64_bf16s<<<nb_g, 256, 0, stream>>>(x, W1, dinv, xs, n);
    gcn_gather_kernel<<<nb_nw, 256, 0, stream>>>(xs, dinv, rowptr, cnt, esrc,
                                                 b1, bufB, n, 1);                   // x1 -> B

    // ---- TransformerConv ----
    gemm_qkvs<<<nb_g, 256, 0, stream>>>(bufB, Wq, bq, Wk, bk, Wv, bv, Ws, bs,
                                        bufA, kv, out, n);                          // q, kv, skip
    attn_gather_kernel<<<nb_nw, 256, 0, stream>>>(bufA, kv, out,
                                                  rowptr, cnt, esrc, bufB, n);      // x2 -> B

    // ---- GCN layer 2 -> out ----
    gemm64_bf16s<<<nb_g, 256, 0, stream>>>(bufB, W2, dinv, xs, n);
    gcn_gather_kernel<<<nb_nw, 256, 0, stream>>>(xs, dinv, rowptr, cnt, esrc,
                                                 b2, out, n, 0);
}

// Round 7
// 245.628 us; speedup vs baseline: 4.1361x; 1.0377x over previous
//
#include <hip/hip_runtime.h>
#include <math.h>

// ---------------------------------------------------------------------------
// GraphTransformer: GCNConv(64->64)+ReLU -> TransformerConv(h=1) -> GCNConv(64->64)
// N=50000, E=800000, D=64, fp32 in/out.
// Round 7:
//  * fusedA: GCN1 gather (group-per-node, no merges) -> x1 in LDS -> QKVS GEMM
//  * fusedB: attn gather (group-per-node online softmax) -> x2 in LDS -> W2 GEMM
//  * x1/x2 never materialized in global. CSR build unchanged (2-phase binning).
// ---------------------------------------------------------------------------

#define D 64
#define BKT_SHIFT 9              // 512 nodes per bucket
#define CAP 12288                // staging capacity per bucket (avg ~8163)
#define CHUNK 4096               // edges per workgroup in binA

// ---- bf16 helpers (RNE) ----------------------------------------------------
__device__ __forceinline__ unsigned short f2bf(float f) {
    unsigned int u = __float_as_uint(f);
    u += 0x7FFFu + ((u >> 16) & 1u);
    return (unsigned short)(u >> 16);
}
#define BF_LO(u) __uint_as_float((u) << 16)
#define BF_HI(u) __uint_as_float((u) & 0xFFFF0000u)

// ============================ CSR build ====================================

__global__ void init_gcursor(int* __restrict__ gcursor) {
    if (threadIdx.x < 128) gcursor[threadIdx.x] = 0;
}

__global__ __launch_bounds__(256) void binA_kernel(const int* __restrict__ src,
                                                   const int* __restrict__ dst,
                                                   int* __restrict__ gcursor,
                                                   unsigned int* __restrict__ staging,
                                                   int e, int nbkt) {
    __shared__ int cntB[128];
    __shared__ int offB[128];
    __shared__ int curB[128];
    __shared__ int gbase[128];
    __shared__ unsigned int pairs[CHUNK];
    __shared__ unsigned char bkt[CHUNK];

    int t = threadIdx.x;
    int e0 = blockIdx.x * CHUNK;
    int ecnt = min(CHUNK, e - e0);

    if (t < 128) cntB[t] = 0;
    __syncthreads();

    int myS[CHUNK / 256], myD[CHUNK / 256];
    #pragma unroll
    for (int i = 0; i < CHUNK / 256; ++i) {
        int idx = t + 256 * i;
        if (idx < ecnt) {
            myS[i] = src[e0 + idx];
            myD[i] = dst[e0 + idx];
            atomicAdd(&cntB[myD[i] >> BKT_SHIFT], 1);
        }
    }
    __syncthreads();
    if (t < 128) offB[t] = cntB[t];
    __syncthreads();
    for (int off = 1; off < 128; off <<= 1) {
        int add = (t < 128 && t >= off) ? offB[t - off] : 0;
        __syncthreads();
        if (t < 128) offB[t] += add;
        __syncthreads();
    }
    if (t < 128) {
        int excl = offB[t] - cntB[t];
        offB[t] = excl;
        curB[t] = excl;
        if (t < nbkt && cntB[t] > 0) gbase[t] = atomicAdd(&gcursor[t], cntB[t]);
    }
    __syncthreads();
    #pragma unroll
    for (int i = 0; i < CHUNK / 256; ++i) {
        int idx = t + 256 * i;
        if (idx < ecnt) {
            int b = myD[i] >> BKT_SHIFT;
            int p = atomicAdd(&curB[b], 1);
            pairs[p] = ((unsigned int)myD[i] << 16) | (unsigned int)myS[i];
            bkt[p] = (unsigned char)b;
        }
    }
    __syncthreads();
    for (int p = t; p < ecnt; p += 256) {
        int b = bkt[p];
        staging[(size_t)b * CAP + gbase[b] + (p - offB[b])] = pairs[p];
    }
}

__global__ __launch_bounds__(256) void binB_kernel(const int* __restrict__ gcursor,
                                                   const unsigned int* __restrict__ staging,
                                                   unsigned short* __restrict__ esrc,
                                                   int* __restrict__ cnt,
                                                   int* __restrict__ rowptr,
                                                   float* __restrict__ dinv,
                                                   int n, int nbkt) {
    __shared__ int bpre[128];
    __shared__ int c512[512];
    __shared__ int o512[512];
    int t = threadIdx.x;
    int b = blockIdx.x;

    if (t < 128) bpre[t] = (t < nbkt) ? gcursor[t] : 0;
    __syncthreads();
    for (int off = 1; off < 128; off <<= 1) {
        int add = (t < 128 && t >= off) ? bpre[t - off] : 0;
        __syncthreads();
        if (t < 128) bpre[t] += add;
        __syncthreads();
    }
    int base_b = (b == 0) ? 0 : bpre[b - 1];
    int cnt_b = gcursor[b];
    int lo = b << BKT_SHIFT;

    c512[t] = 0; c512[t + 256] = 0;
    __syncthreads();
    const unsigned int* st = staging + (size_t)b * CAP;
    for (int i = t; i < cnt_b; i += 256)
        atomicAdd(&c512[(int)(st[i] >> 16) - lo], 1);
    __syncthreads();
    o512[t] = c512[t]; o512[t + 256] = c512[t + 256];
    __syncthreads();
    for (int off = 1; off < 512; off <<= 1) {
        int a1 = (t >= off) ? o512[t - off] : 0;
        int a2 = o512[t + 256 - off];
        __syncthreads();
        o512[t] += a1; o512[t + 256] += a2;
        __syncthreads();
    }
    int e1 = o512[t] - c512[t];
    int e2 = o512[t + 256] - c512[t + 256];
    __syncthreads();
    o512[t] = e1; o512[t + 256] = e2;
    __syncthreads();
    for (int i = t; i < 512; i += 256) {
        int g = lo + i;
        if (g < n) {
            int c = c512[i];
            cnt[g] = c;
            rowptr[g] = base_b + o512[i];
            dinv[g] = rsqrtf((float)c + 1.0f);
        }
    }
    __syncthreads();
    for (int i = t; i < cnt_b; i += 256) {
        unsigned int pk = st[i];
        int local = (int)(pk >> 16) - lo;
        int p = atomicAdd(&o512[local], 1);
        esrc[base_b + p] = (unsigned short)(pk & 0xFFFFu);
    }
}

// ============ GEMM 64x64, epilogue: bf16 output pre-scaled by dinv =========
__global__ __launch_bounds__(256) void gemm64_bf16s(const float* __restrict__ X,
                                                    const float* __restrict__ W,
                                                    const float* __restrict__ dinv,
                                                    unsigned short* __restrict__ xs, int n) {
    __shared__ float sX[64][68];
    __shared__ float sW[64 * 64];
    int t = threadIdx.x;
    int base = blockIdx.x * 64;
    #pragma unroll
    for (int i = 0; i < 4; ++i) {
        int f = t * 4 + i * 1024;
        *(float4*)&sW[f] = *(const float4*)&W[f];
        int r = f >> 6, c = f & 63;
        int row = base + r;
        float4 xv = (row < n) ? *(const float4*)&X[(size_t)row * D + c]
                              : make_float4(0.f, 0.f, 0.f, 0.f);
        *(float4*)&sX[r][c] = xv;
    }
    __syncthreads();

    int cg = t & 15, rg = t >> 4;
    int j0 = cg * 4, r0 = rg * 4;
    float acc[4][4];
    #pragma unroll
    for (int a = 0; a < 4; ++a)
        #pragma unroll
        for (int c = 0; c < 4; ++c) acc[a][c] = 0.0f;

    #pragma unroll 4
    for (int kk = 0; kk < 64; kk += 4) {
        float4 w0 = *(const float4*)&sW[(kk + 0) * 64 + j0];
        float4 w1 = *(const float4*)&sW[(kk + 1) * 64 + j0];
        float4 w2 = *(const float4*)&sW[(kk + 2) * 64 + j0];
        float4 w3 = *(const float4*)&sW[(kk + 3) * 64 + j0];
        #pragma unroll
        for (int a = 0; a < 4; ++a) {
            float4 xv = *(const float4*)&sX[r0 + a][kk];
            acc[a][0] = fmaf(xv.x, w0.x, acc[a][0]); acc[a][1] = fmaf(xv.x, w0.y, acc[a][1]);
            acc[a][2] = fmaf(xv.x, w0.z, acc[a][2]); acc[a][3] = fmaf(xv.x, w0.w, acc[a][3]);
            acc[a][0] = fmaf(xv.y, w1.x, acc[a][0]); acc[a][1] = fmaf(xv.y, w1.y, acc[a][1]);
            acc[a][2] = fmaf(xv.y, w1.z, acc[a][2]); acc[a][3] = fmaf(xv.y, w1.w, acc[a][3]);
            acc[a][0] = fmaf(xv.z, w2.x, acc[a][0]); acc[a][1] = fmaf(xv.z, w2.y, acc[a][1]);
            acc[a][2] = fmaf(xv.z, w2.z, acc[a][2]); acc[a][3] = fmaf(xv.z, w2.w, acc[a][3]);
            acc[a][0] = fmaf(xv.w, w3.x, acc[a][0]); acc[a][1] = fmaf(xv.w, w3.y, acc[a][1]);
            acc[a][2] = fmaf(xv.w, w3.z, acc[a][2]); acc[a][3] = fmaf(xv.w, w3.w, acc[a][3]);
        }
    }

    #pragma unroll
    for (int a = 0; a < 4; ++a) {
        int row = base + r0 + a;
        if (row < n) {
            float dv = dinv[row];
            ushort4 h;
            h.x = f2bf(acc[a][0] * dv);
            h.y = f2bf(acc[a][1] * dv);
            h.z = f2bf(acc[a][2] * dv);
            h.w = f2bf(acc[a][3] * dv);
            *(ushort4*)&xs[(size_t)row * D + j0] = h;
        }
    }
}

// ====== fusedA: GCN1 gather (group-per-node) -> x1 in LDS -> QKVS GEMM =====
// gather: out_row = relu(dinv[d]*(xs[d] + sum xs[s]) + b1) written to sX.
// GEMM: q = (x1@Wq+bq)/8 fp32; kv = bf16(k|v); skip = x1@Ws+bs fp32.
__global__ __launch_bounds__(256) void fusedA_kernel(const unsigned short* __restrict__ xs,
                                                     const float* __restrict__ dinv,
                                                     const int* __restrict__ rowptr,
                                                     const int* __restrict__ cnt,
                                                     const unsigned short* __restrict__ esrc,
                                                     const float* __restrict__ b1,
                                                     const float* __restrict__ Wq,
                                                     const float* __restrict__ bq,
                                                     const float* __restrict__ Wk,
                                                     const float* __restrict__ bk,
                                                     const float* __restrict__ Wv,
                                                     const float* __restrict__ bv,
                                                     const float* __restrict__ Ws,
                                                     const float* __restrict__ bs,
                                                     float* __restrict__ Yq,
                                                     unsigned short* __restrict__ kv,
                                                     float* __restrict__ Ysk, int n) {
    __shared__ float sX[64][68];
    __shared__ float sW[64 * 64];
    int t = threadIdx.x;
    int base = blockIdx.x * 64;
    int wid = t >> 6, lane = t & 63;
    int grp = lane >> 3, sub = lane & 7;
    int j0 = sub * 8;

    float4 bb0 = *(const float4*)&b1[j0];
    float4 bb1 = *(const float4*)&b1[j0 + 4];

    // ---- gather phase: each 8-lane group owns 2 nodes sequentially ----
    #pragma unroll
    for (int slot = 0; slot < 2; ++slot) {
        int local = wid * 16 + slot * 8 + grp;
        int node = base + local;
        float a[8] = {0.f, 0.f, 0.f, 0.f, 0.f, 0.f, 0.f, 0.f};
        float4 o0 = make_float4(0.f, 0.f, 0.f, 0.f);
        float4 o1 = make_float4(0.f, 0.f, 0.f, 0.f);
        if (node < n) {
            float dd = dinv[node];
            int start = rowptr[node], deg = cnt[node];
            uint4 sr = *(const uint4*)&xs[(size_t)node * D + j0];   // self term
            a[0] += BF_LO(sr.x); a[1] += BF_HI(sr.x);
            a[2] += BF_LO(sr.y); a[3] += BF_HI(sr.y);
            a[4] += BF_LO(sr.z); a[5] += BF_HI(sr.z);
            a[6] += BF_LO(sr.w); a[7] += BF_HI(sr.w);
            int sNext = (deg > 0) ? esrc[start] : 0;
            for (int i = 0; i < deg; ++i) {
                int s = sNext;
                if (i + 1 < deg) sNext = esrc[start + i + 1];
                uint4 r = *(const uint4*)&xs[(size_t)s * D + j0];
                a[0] += BF_LO(r.x); a[1] += BF_HI(r.x);
                a[2] += BF_LO(r.y); a[3] += BF_HI(r.y);
                a[4] += BF_LO(r.z); a[5] += BF_HI(r.z);
                a[6] += BF_LO(r.w); a[7] += BF_HI(r.w);
            }
            o0.x = fmaxf(fmaf(dd, a[0], bb0.x), 0.f);
            o0.y = fmaxf(fmaf(dd, a[1], bb0.y), 0.f);
            o0.z = fmaxf(fmaf(dd, a[2], bb0.z), 0.f);
            o0.w = fmaxf(fmaf(dd, a[3], bb0.w), 0.f);
            o1.x = fmaxf(fmaf(dd, a[4], bb1.x), 0.f);
            o1.y = fmaxf(fmaf(dd, a[5], bb1.y), 0.f);
            o1.z = fmaxf(fmaf(dd, a[6], bb1.z), 0.f);
            o1.w = fmaxf(fmaf(dd, a[7], bb1.w), 0.f);
        }
        *(float4*)&sX[local][j0] = o0;
        *(float4*)&sX[local][j0 + 4] = o1;
    }

    // ---- GEMM phase: 4 weight matrices ----
    int cg = t & 15, rg = t >> 4;
    int gj0 = cg * 4, r0 = rg * 4;

    #pragma unroll 1
    for (int w4 = 0; w4 < 4; ++w4) {
        const float* W = (w4 == 0) ? Wq : (w4 == 1) ? Wk : (w4 == 2) ? Wv : Ws;
        const float* B = (w4 == 0) ? bq : (w4 == 1) ? bk : (w4 == 2) ? bv : bs;
        __syncthreads();   // gather done (w4=0) / previous readers done
        #pragma unroll
        for (int i = 0; i < 4; ++i) {
            int f = t * 4 + i * 1024;
            *(float4*)&sW[f] = *(const float4*)&W[f];
        }
        __syncthreads();

        float acc[4][4];
        #pragma unroll
        for (int a = 0; a < 4; ++a)
            #pragma unroll
            for (int c = 0; c < 4; ++c) acc[a][c] = 0.0f;

        #pragma unroll 4
        for (int kk = 0; kk < 64; kk += 4) {
            float4 w0 = *(const float4*)&sW[(kk + 0) * 64 + gj0];
            float4 w1 = *(const float4*)&sW[(kk + 1) * 64 + gj0];
            float4 w2 = *(const float4*)&sW[(kk + 2) * 64 + gj0];
            float4 w3 = *(const float4*)&sW[(kk + 3) * 64 + gj0];
            #pragma unroll
            for (int a = 0; a < 4; ++a) {
                float4 xv = *(const float4*)&sX[r0 + a][kk];
                acc[a][0] = fmaf(xv.x, w0.x, acc[a][0]); acc[a][1] = fmaf(xv.x, w0.y, acc[a][1]);
                acc[a][2] = fmaf(xv.x, w0.z, acc[a][2]); acc[a][3] = fmaf(xv.x, w0.w, acc[a][3]);
                acc[a][0] = fmaf(xv.y, w1.x, acc[a][0]); acc[a][1] = fmaf(xv.y, w1.y, acc[a][1]);
                acc[a][2] = fmaf(xv.y, w1.z, acc[a][2]); acc[a][3] = fmaf(xv.y, w1.w, acc[a][3]);
                acc[a][0] = fmaf(xv.z, w2.x, acc[a][0]); acc[a][1] = fmaf(xv.z, w2.y, acc[a][1]);
                acc[a][2] = fmaf(xv.z, w2.z, acc[a][2]); acc[a][3] = fmaf(xv.z, w2.w, acc[a][3]);
                acc[a][0] = fmaf(xv.w, w3.x, acc[a][0]); acc[a][1] = fmaf(xv.w, w3.y, acc[a][1]);
                acc[a][2] = fmaf(xv.w, w3.z, acc[a][2]); acc[a][3] = fmaf(xv.w, w3.w, acc[a][3]);
            }
        }

        float4 bb = *(const float4*)&B[gj0];
        if (w4 == 0) {
            #pragma unroll
            for (int a = 0; a < 4; ++a) {
                int row = base + r0 + a;
                if (row < n) {
                    float4 o = make_float4((acc[a][0] + bb.x) * 0.125f,
                                           (acc[a][1] + bb.y) * 0.125f,
                                           (acc[a][2] + bb.z) * 0.125f,
                                           (acc[a][3] + bb.w) * 0.125f);
                    *(float4*)&Yq[(size_t)row * D + gj0] = o;
                }
            }
        } else if (w4 == 3) {
            #pragma unroll
            for (int a = 0; a < 4; ++a) {
                int row = base + r0 + a;
                if (row < n) {
                    float4 o = make_float4(acc[a][0] + bb.x, acc[a][1] + bb.y,
                                           acc[a][2] + bb.z, acc[a][3] + bb.w);
                    *(float4*)&Ysk[(size_t)row * D + gj0] = o;
                }
            }
        } else {
            int off = (w4 == 1) ? 0 : 64;
            #pragma unroll
            for (int a = 0; a < 4; ++a) {
                int row = base + r0 + a;
                if (row < n) {
                    ushort4 h;
                    h.x = f2bf(acc[a][0] + bb.x);
                    h.y = f2bf(acc[a][1] + bb.y);
                    h.z = f2bf(acc[a][2] + bb.z);
                    h.w = f2bf(acc[a][3] + bb.w);
                    *(ushort4*)&kv[(size_t)row * 128 + off + gj0] = h;
                }
            }
        }
    }
}

// ====== fusedB: attn gather (group-per-node softmax) -> x2 LDS -> W2 GEMM ==
// epilogue: xs2[row] = bf16((x2@W2)[row] * dinv[row])
__global__ __launch_bounds__(256) void fusedB_kernel(const float* __restrict__ q,
                                                     const unsigned short* __restrict__ kv,
                                                     const float* __restrict__ skip,
                                                     const float* __restrict__ dinv,
                                                     const int* __restrict__ rowptr,
                                                     const int* __restrict__ cnt,
                                                     const unsigned short* __restrict__ esrc,
                                                     const float* __restrict__ W2,
                                                     unsigned short* __restrict__ xs2, int n) {
    __shared__ float sX[64][68];
    __shared__ float sW[64 * 64];
    int t = threadIdx.x;
    int base = blockIdx.x * 64;
    int wid = t >> 6, lane = t & 63;
    int grp = lane >> 3, sub = lane & 7;
    int j0 = sub * 8;

    // stage W2 while gathering
    #pragma unroll
    for (int i = 0; i < 4; ++i) {
        int f = t * 4 + i * 1024;
        *(float4*)&sW[f] = *(const float4*)&W2[f];
    }

    // ---- attn gather phase: each 8-lane group owns 2 nodes sequentially ----
    #pragma unroll
    for (int slot = 0; slot < 2; ++slot) {
        int local = wid * 16 + slot * 8 + grp;
        int node = base + local;
        float4 o0 = make_float4(0.f, 0.f, 0.f, 0.f);
        float4 o1 = make_float4(0.f, 0.f, 0.f, 0.f);
        if (node < n) {
            int start = rowptr[node], deg = cnt[node];
            float4 q0 = *(const float4*)&q[(size_t)node * D + j0];     // pre-scaled 1/8
            float4 q1 = *(const float4*)&q[(size_t)node * D + j0 + 4];
            float4 s0 = *(const float4*)&skip[(size_t)node * D + j0];
            float4 s1 = *(const float4*)&skip[(size_t)node * D + j0 + 4];
            float m = -INFINITY, z = 0.0f;
            float a[8] = {0.f, 0.f, 0.f, 0.f, 0.f, 0.f, 0.f, 0.f};
            int sNext = (deg > 0) ? esrc[start] : 0;
            for (int i = 0; i < deg; ++i) {
                int s = sNext;
                if (i + 1 < deg) sNext = esrc[start + i + 1];
                const unsigned short* row = kv + (size_t)s * 128;
                uint4 kr = *(const uint4*)&row[j0];
                uint4 vr = *(const uint4*)&row[64 + j0];
                float p = q0.x * BF_LO(kr.x) + q0.y * BF_HI(kr.x)
                        + q0.z * BF_LO(kr.y) + q0.w * BF_HI(kr.y)
                        + q1.x * BF_LO(kr.z) + q1.y * BF_HI(kr.z)
                        + q1.z * BF_LO(kr.w) + q1.w * BF_HI(kr.w);
                p += __shfl_xor(p, 1, 64);
                p += __shfl_xor(p, 2, 64);
                p += __shfl_xor(p, 4, 64);
                float mn = fmaxf(m, p);
                float corr = __expf(m - mn);     // first edge: exp(-inf)=0
                float w = __expf(p - mn);
                z = z * corr + w;
                a[0] = fmaf(w, BF_LO(vr.x), a[0] * corr);
                a[1] = fmaf(w, BF_HI(vr.x), a[1] * corr);
                a[2] = fmaf(w, BF_LO(vr.y), a[2] * corr);
                a[3] = fmaf(w, BF_HI(vr.y), a[3] * corr);
                a[4] = fmaf(w, BF_LO(vr.z), a[4] * corr);
                a[5] = fmaf(w, BF_HI(vr.z), a[5] * corr);
                a[6] = fmaf(w, BF_LO(vr.w), a[6] * corr);
                a[7] = fmaf(w, BF_HI(vr.w), a[7] * corr);
                m = mn;
            }
            if (deg > 0) {
                float inv = 1.0f / z;
                o0.x = fmaf(a[0], inv, s0.x); o0.y = fmaf(a[1], inv, s0.y);
                o0.z = fmaf(a[2], inv, s0.z); o0.w = fmaf(a[3], inv, s0.w);
                o1.x = fmaf(a[4], inv, s1.x); o1.y = fmaf(a[5], inv, s1.y);
                o1.z = fmaf(a[6], inv, s1.z); o1.w = fmaf(a[7], inv, s1.w);
            } else {
                o0 = s0; o1 = s1;
            }
        }
        *(float4*)&sX[local][j0] = o0;
        *(float4*)&sX[local][j0 + 4] = o1;
    }
    __syncthreads();

    // ---- GEMM phase: x2 @ W2, epilogue bf16 * dinv ----
    int cg = t & 15, rg = t >> 4;
    int gj0 = cg * 4, r0 = rg * 4;
    float acc[4][4];
    #pragma unroll
    for (int a = 0; a < 4; ++a)
        #pragma unroll
        for (int c = 0; c < 4; ++c) acc[a][c] = 0.0f;

    #pragma unroll 4
    for (int kk = 0; kk < 64; kk += 4) {
        float4 w0 = *(const float4*)&sW[(kk + 0) * 64 + gj0];
        float4 w1 = *(const float4*)&sW[(kk + 1) * 64 + gj0];
        float4 w2 = *(const float4*)&sW[(kk + 2) * 64 + gj0];
        float4 w3 = *(const float4*)&sW[(kk + 3) * 64 + gj0];
        #pragma unroll
        for (int a = 0; a < 4; ++a) {
            float4 xv = *(const float4*)&sX[r0 + a][kk];
            acc[a][0] = fmaf(xv.x, w0.x, acc[a][0]); acc[a][1] = fmaf(xv.x, w0.y, acc[a][1]);
            acc[a][2] = fmaf(xv.x, w0.z, acc[a][2]); acc[a][3] = fmaf(xv.x, w0.w, acc[a][3]);
            acc[a][0] = fmaf(xv.y, w1.x, acc[a][0]); acc[a][1] = fmaf(xv.y, w1.y, acc[a][1]);
            acc[a][2] = fmaf(xv.y, w1.z, acc[a][2]); acc[a][3] = fmaf(xv.y, w1.w, acc[a][3]);
            acc[a][0] = fmaf(xv.z, w2.x, acc[a][0]); acc[a][1] = fmaf(xv.z, w2.y, acc[a][1]);
            acc[a][2] = fmaf(xv.z, w2.z, acc[a][2]); acc[a][3] = fmaf(xv.z, w2.w, acc[a][3]);
            acc[a][0] = fmaf(xv.w, w3.x, acc[a][0]); acc[a][1] = fmaf(xv.w, w3.y, acc[a][1]);
            acc[a][2] = fmaf(xv.w, w3.z, acc[a][2]); acc[a][3] = fmaf(xv.w, w3.w, acc[a][3]);
        }
    }

    #pragma unroll
    for (int a = 0; a < 4; ++a) {
        int row = base + r0 + a;
        if (row < n) {
            float dv = dinv[row];
            ushort4 h;
            h.x = f2bf(acc[a][0] * dv);
            h.y = f2bf(acc[a][1] * dv);
            h.z = f2bf(acc[a][2] * dv);
            h.w = f2bf(acc[a][3] * dv);
            *(ushort4*)&xs2[(size_t)row * D + gj0] = h;
        }
    }
}

// ===================== GCN gather (bf16 rows, 8x8 grouped) =================
__global__ __launch_bounds__(256) void gcn_gather_kernel(const unsigned short* __restrict__ xs,
                                                         const float* __restrict__ dinv,
                                                         const int* __restrict__ rowptr,
                                                         const int* __restrict__ cnt,
                                                         const unsigned short* __restrict__ esrc,
                                                         const float* __restrict__ bias,
                                                         float* __restrict__ out,
                                                         int n, int relu) {
    int node = (blockIdx.x * blockDim.x + threadIdx.x) >> 6;
    if (node >= n) return;
    int lane = threadIdx.x & 63;
    int grp = lane >> 3;
    int sub = lane & 7;
    int j0 = sub * 8;

    int start = rowptr[node], deg = cnt[node];

    float a[8] = {0.f, 0.f, 0.f, 0.f, 0.f, 0.f, 0.f, 0.f};
    int i = grp;
    int sNext = (i < deg) ? esrc[start + i] : 0;
    for (; i < deg; i += 8) {
        int s = sNext;
        int in = i + 8;
        if (in < deg) sNext = esrc[start + in];
        uint4 r = *(const uint4*)&xs[(size_t)s * D + j0];
        a[0] += BF_LO(r.x); a[1] += BF_HI(r.x);
        a[2] += BF_LO(r.y); a[3] += BF_HI(r.y);
        a[4] += BF_LO(r.z); a[5] += BF_HI(r.z);
        a[6] += BF_LO(r.w); a[7] += BF_HI(r.w);
    }
    #pragma unroll
    for (int off = 8; off < 64; off <<= 1) {
        #pragma unroll
        for (int c = 0; c < 8; ++c) a[c] += __shfl_xor(a[c], off, 64);
    }

    if (grp == 0) {
        float dd = dinv[node];
        uint4 sr = *(const uint4*)&xs[(size_t)node * D + j0];
        a[0] += BF_LO(sr.x); a[1] += BF_HI(sr.x);
        a[2] += BF_LO(sr.y); a[3] += BF_HI(sr.y);
        a[4] += BF_LO(sr.z); a[5] += BF_HI(sr.z);
        a[6] += BF_LO(sr.w); a[7] += BF_HI(sr.w);
        float4 b0 = *(const float4*)&bias[j0];
        float4 b1 = *(const float4*)&bias[j0 + 4];
        float o[8];
        o[0] = fmaf(dd, a[0], b0.x); o[1] = fmaf(dd, a[1], b0.y);
        o[2] = fmaf(dd, a[2], b0.z); o[3] = fmaf(dd, a[3], b0.w);
        o[4] = fmaf(dd, a[4], b1.x); o[5] = fmaf(dd, a[5], b1.y);
        o[6] = fmaf(dd, a[6], b1.z); o[7] = fmaf(dd, a[7], b1.w);
        if (relu) {
            #pragma unroll
            for (int c = 0; c < 8; ++c) o[c] = fmaxf(o[c], 0.f);
        }
        *(float4*)&out[(size_t)node * D + j0] = make_float4(o[0], o[1], o[2], o[3]);
        *(float4*)&out[(size_t)node * D + j0 + 4] = make_float4(o[4], o[5], o[6], o[7]);
    }
}

// =============================== launch ====================================

extern "C" void kernel_launch(void* const* d_in, const int* in_sizes, int n_in,
                              void* d_out, int out_size, void* d_ws, size_t ws_size,
                              hipStream_t stream) {
    const float* x  = (const float*)d_in[0];
    const int*   ei = (const int*)d_in[1];
    const float* W1 = (const float*)d_in[2];
    const float* b1 = (const float*)d_in[3];
    const float* Wq = (const float*)d_in[4];
    const float* bq = (const float*)d_in[5];
    const float* Wk = (const float*)d_in[6];
    const float* bk = (const float*)d_in[7];
    const float* Wv = (const float*)d_in[8];
    const float* bv = (const float*)d_in[9];
    const float* Ws = (const float*)d_in[10];
    const float* bs = (const float*)d_in[11];
    const float* W2 = (const float*)d_in[12];
    const float* b2 = (const float*)d_in[13];
    float* out = (float*)d_out;

    const int n = in_sizes[0] / D;   // 50000  (< 65536 for 16-bit packing)
    const int e = in_sizes[1] / 2;   // 800000
    const int* src = ei;
    const int* dst = ei + e;
    const int n64 = n * D;
    const int nbkt = (n + (1 << BKT_SHIFT) - 1) >> BKT_SHIFT;   // 98

    char* w = (char*)d_ws;
    auto carve = [&](size_t bytes) {
        char* p = w;
        w += (bytes + 255) & ~(size_t)255;
        return p;
    };
    int* gcursor            = (int*)carve(128 * 4);
    unsigned int* staging   = (unsigned int*)carve((size_t)nbkt * CAP * 4);
    unsigned short* esrc    = (unsigned short*)carve((size_t)e * 2);
    int* cnt                = (int*)carve((size_t)n * 4);
    int* rowptr             = (int*)carve((size_t)n * 4);
    float* dinv             = (float*)carve((size_t)n * 4);
    float* bufQ             = (float*)carve((size_t)n64 * 4);   // q (pre-scaled)
    unsigned short* xs      = (unsigned short*)carve((size_t)n64 * 2);  // xw*dinv bf16 (L1/L2 reuse)
    unsigned short* kv      = (unsigned short*)carve((size_t)n64 * 4);  // k|v bf16

    const int nb_binA = (e + CHUNK - 1) / CHUNK;   // 196
    const int nb_nw   = (n + 3) / 4;               // wave-per-node (final gather)
    const int nb_g    = (n + 63) / 64;             // 64 rows/block

    // ---- CSR build (2-phase binning) ----
    init_gcursor<<<1, 128, 0, stream>>>(gcursor);
    binA_kernel<<<nb_binA, 256, 0, stream>>>(src, dst, gcursor, staging, e, nbkt);
    binB_kernel<<<nbkt, 256, 0, stream>>>(gcursor, staging, esrc, cnt, rowptr, dinv, n, nbkt);

    // ---- layer 1 GEMM: xs = bf16((x@W1)*dinv) ----
    gemm64_bf16s<<<nb_g, 256, 0, stream>>>(x, W1, dinv, xs, n);

    // ---- fused: GCN1 gather -> x1 (LDS) -> QKVS GEMM ----
    fusedA_kernel<<<nb_g, 256, 0, stream>>>(xs, dinv, rowptr, cnt, esrc, b1,
                                            Wq, bq, Wk, bk, Wv, bv, Ws, bs,
                                            bufQ, kv, out, n);   // skip -> out

    // ---- fused: attn gather -> x2 (LDS) -> W2 GEMM -> xs (reused) ----
    fusedB_kernel<<<nb_g, 256, 0, stream>>>(bufQ, kv, out, dinv,
                                            rowptr, cnt, esrc, W2, xs, n);

    // ---- final GCN2 gather -> out ----
    gcn_gather_kernel<<<nb_nw, 256, 0, stream>>>(xs, dinv, rowptr, cnt, esrc,
                                                 b2, out, n, 0);
}